// Round 9
// baseline (15590.344 us; speedup 1.0000x reference)
//
#include <hip/hip_runtime.h>
#include <hip/hip_bf16.h>
#include <stdint.h>

#define T_STEPS 64
#define BATCH   16
#define NROWS   1024          // T*B
#define NTOKENS 10000
#define NTOKPAD 10048         // 157*64
#define NBLK_N  157
#define BXPAD   160           // 8 XCDs * 20 bx-chunks
#define D_INP   280
#define D_HID   960
#define D_LAST  620
#define NEXP    15
#define KPAD    288           // 280 padded to 9*32
#define MROWS   (NROWS * NEXP)  // 15360
#define NLAT    4200          // NEXP*D_INP
#define NLATPAD 4224          // 66*64
#define KLAT    640           // 620 padded to 20*32

typedef __attribute__((ext_vector_type(8))) short bf16x8;
typedef __attribute__((ext_vector_type(4))) float f32x4;

__device__ inline float log1p_cr(float x) { return (float)log1p((double)x); }
__device__ inline float exp_cr(float x)   { return (float)exp((double)x); }

__device__ inline ushort f2bf(float f) {
  uint32_t u = __float_as_uint(f);
  uint32_t r = (u + 0x7FFFu + ((u >> 16) & 1u)) >> 16;  // RNE
  return (ushort)r;
}

__device__ inline void xcd_decode(int bid, int* bx, int* by) {
  int x = bid & 7, k = bid >> 3;
  *bx = x * 20 + (k % 20);
  *by = k / 20;
}

// ---------------------------------------------------------------------------
__global__ void embed_kernel(const int* __restrict__ tokens,
                             const float* __restrict__ W_emb,
                             float* __restrict__ emb) {
  int n = blockIdx.x;
  int tok = tokens[n];
  for (int c = threadIdx.x; c < D_INP; c += blockDim.x)
    emb[(size_t)n * D_INP + c] = W_emb[(size_t)tok * D_INP + c];
}

// C[M][N] = A[M][K] @ B[N][K]^T + bias0 + bias1, f32 (feeds gates: precision)
#define GBM 128
#define GBN 128
#define GBK 16
__global__ __launch_bounds__(256) void gemm_abt(
    const float* __restrict__ A, const float* __restrict__ B,
    const float* __restrict__ bias0, const float* __restrict__ bias1,
    float* __restrict__ C, int M, int N, int K, int activation) {
  __shared__ float As[GBK][GBM + 4];
  __shared__ float Bs[GBK][GBN + 4];
  int bm = blockIdx.y * GBM, bn = blockIdx.x * GBN;
  int tx = threadIdx.x & 15, ty = threadIdx.x >> 4;
  int ml = threadIdx.x >> 2;
  int kc4 = (threadIdx.x & 3) * 4;
  float acc[8][8] = {};
  for (int k0 = 0; k0 < K; k0 += GBK) {
#pragma unroll
    for (int rep = 0; rep < 2; ++rep) {
      int m = ml + rep * 64;
      int gk = k0 + kc4;
      {
        int gm = bm + m;
        float4 v = {0.f, 0.f, 0.f, 0.f};
        if (gk + 3 < K) v = *(const float4*)&A[(size_t)gm * K + gk];
        else {
          float t0 = (gk + 0 < K) ? A[(size_t)gm * K + gk + 0] : 0.f;
          float t1 = (gk + 1 < K) ? A[(size_t)gm * K + gk + 1] : 0.f;
          float t2 = (gk + 2 < K) ? A[(size_t)gm * K + gk + 2] : 0.f;
          float t3 = (gk + 3 < K) ? A[(size_t)gm * K + gk + 3] : 0.f;
          v = {t0, t1, t2, t3};
        }
        As[kc4 + 0][m] = v.x; As[kc4 + 1][m] = v.y;
        As[kc4 + 2][m] = v.z; As[kc4 + 3][m] = v.w;
      }
      {
        int gn = bn + m;
        float4 v = {0.f, 0.f, 0.f, 0.f};
        if (gn < N) {
          if (gk + 3 < K) v = *(const float4*)&B[(size_t)gn * K + gk];
          else {
            float t0 = (gk + 0 < K) ? B[(size_t)gn * K + gk + 0] : 0.f;
            float t1 = (gk + 1 < K) ? B[(size_t)gn * K + gk + 1] : 0.f;
            float t2 = (gk + 2 < K) ? B[(size_t)gn * K + gk + 2] : 0.f;
            float t3 = (gk + 3 < K) ? B[(size_t)gn * K + gk + 3] : 0.f;
            v = {t0, t1, t2, t3};
          }
        }
        Bs[kc4 + 0][m] = v.x; Bs[kc4 + 1][m] = v.y;
        Bs[kc4 + 2][m] = v.z; Bs[kc4 + 3][m] = v.w;
      }
    }
    __syncthreads();
#pragma unroll
    for (int kk = 0; kk < GBK; ++kk) {
      float4 a0 = *(const float4*)&As[kk][ty * 8];
      float4 a1 = *(const float4*)&As[kk][ty * 8 + 4];
      float4 b0 = *(const float4*)&Bs[kk][tx * 8];
      float4 b1 = *(const float4*)&Bs[kk][tx * 8 + 4];
      float a[8] = {a0.x, a0.y, a0.z, a0.w, a1.x, a1.y, a1.z, a1.w};
      float b[8] = {b0.x, b0.y, b0.z, b0.w, b1.x, b1.y, b1.z, b1.w};
#pragma unroll
      for (int i = 0; i < 8; ++i)
#pragma unroll
        for (int j = 0; j < 8; ++j) acc[i][j] += a[i] * b[j];
    }
    __syncthreads();
  }
#pragma unroll
  for (int i = 0; i < 8; ++i) {
    int gm = bm + ty * 8 + i;
#pragma unroll
    for (int j = 0; j < 8; ++j) {
      int gn = bn + tx * 8 + j;
      if (gn < N) {
        float v = acc[i][j];
        if (bias0) v += bias0[gn];
        if (bias1) v += bias1[gn];
        if (activation == 1) v = tanhf(v);
        C[(size_t)gm * N + gn] = v;
      }
    }
  }
}

// ---------------------------------------------------------------------------
// Persistent LSTM v2: j=2 per block, 512 threads (2 j x 16 sub x 16 b),
// grid = H/2 blocks (480/480/310). Weights + h staged in LDS (two halves).
// 8-line arrival counters + master-published "go" epoch (device scope).
// Capacity: LDS 62.5KB -> 2 blocks/CU by LDS; 8 waves/block -> 4 blocks/CU
// by waves; grid 480 <= 512 co-resident guaranteed.
__global__ __launch_bounds__(512) void lstm_persist(
    const float* __restrict__ xih,   // [T][B][4H]
    const float* __restrict__ Whh,   // [4H][H]
    const float* __restrict__ h0,    // [B][H]
    const float* __restrict__ c0,    // [B][H]
    float* __restrict__ hA,          // [H*16] ping
    float* __restrict__ hB,          // [H*16] pong
    float* __restrict__ xout,        // [T][B][H]
    unsigned* __restrict__ sync,     // 8 arrival lines (i*32) + go (8*32)
    int H, int nblocks) {
  __shared__ float wlds[4][2][D_HID];   // 30720 B
  __shared__ float hbuf[480 * 16];      // 30720 B
  __shared__ float red[8][4][16];       // 2048 B
  __shared__ float gsum[2][4][16];      // 512 B
  const int tid = threadIdx.x;
  const int bid = blockIdx.x;
  const int jbase = bid * 2;
  const int jl = tid >> 8;            // 0..1
  const int sub = (tid >> 4) & 15;    // 0..15
  const int b = tid & 15;
  const int wv = tid >> 6;            // 0..7

  // stage weights: 8 rows (4 gates x 2 j) of H floats, coalesced
  for (int r = 0; r < 8; ++r) {
    int g = r >> 1, jj = r & 1;
    const float* src = Whh + (size_t)(g * H + jbase + jj) * H;
    for (int k = tid; k < H; k += 512) wlds[g][jj][k] = src[k];
  }

  const bool isPB = (tid < 32);
  const int pjl = tid >> 4;           // valid when isPB
  const int pb = tid & 15;
  const int pj = jbase + pjl;
  float creg = 0.f;
  float xr0 = 0.f, xr1 = 0.f, xr2 = 0.f, xr3 = 0.f;
  if (isPB) {
    creg = c0[(size_t)pb * H + pj];
    __hip_atomic_store(&hA[pj * 16 + pb], h0[(size_t)pb * H + pj],
                       __ATOMIC_RELAXED, __HIP_MEMORY_SCOPE_AGENT);
    // prefetch xih for t=0
    const float* xr = xih + (size_t)(0 * BATCH + pb) * (4 * H);
    xr0 = xr[0 * H + pj]; xr1 = xr[1 * H + pj];
    xr2 = xr[2 * H + pj]; xr3 = xr[3 * H + pj];
  }
  unsigned* arr = sync + (bid & 7) * 32;
  unsigned* gop = sync + 8 * 32;

  __syncthreads();
  if (tid == 0) {
    __hip_atomic_fetch_add(arr, 1u, __ATOMIC_RELEASE, __HIP_MEMORY_SCOPE_AGENT);
    if (bid == 0) {
      for (;;) {
        unsigned s = 0;
        for (int i = 0; i < 8; ++i)
          s += __hip_atomic_load(sync + i * 32, __ATOMIC_ACQUIRE,
                                 __HIP_MEMORY_SCOPE_AGENT);
        if (s >= (unsigned)nblocks) break;
        __builtin_amdgcn_s_sleep(8);
      }
      __hip_atomic_store(gop, 1u, __ATOMIC_RELEASE, __HIP_MEMORY_SCOPE_AGENT);
    } else {
      while (__hip_atomic_load(gop, __ATOMIC_ACQUIRE, __HIP_MEMORY_SCOPE_AGENT) < 1u)
        __builtin_amdgcn_s_sleep(16);
    }
  }
  __syncthreads();

  const int n1 = 480 * 16 / 4;                         // half-1 float4 count
  const int n2 = (H - 480) * 16 / 4;                   // half-2 float4 count
  for (int t = 0; t < T_STEPS; ++t) {
    const float* hin = (t & 1) ? hB : hA;
    float* hout = (t & 1) ? hA : hB;
    // ---- half 1: stage h[0:480) then dot
    for (int i = tid; i < n1; i += 512)
      ((float4*)hbuf)[i] = ((const float4*)hin)[i];
    __syncthreads();
    float si = 0.f, sf = 0.f, sg = 0.f, so = 0.f;
#pragma unroll 5
    for (int k = sub; k < 480; k += 16) {
      float hv = hbuf[k * 16 + b];
      si += hv * wlds[0][jl][k];
      sf += hv * wlds[1][jl][k];
      sg += hv * wlds[2][jl][k];
      so += hv * wlds[3][jl][k];
    }
    __syncthreads();
    // ---- half 2: stage h[480:H) then dot
    for (int i = tid; i < n2; i += 512)
      ((float4*)hbuf)[i] = ((const float4*)(hin + 480 * 16))[i];
    __syncthreads();
#pragma unroll 5
    for (int k = 480 + sub; k < H; k += 16) {
      float hv = hbuf[(k - 480) * 16 + b];
      si += hv * wlds[0][jl][k];
      sf += hv * wlds[1][jl][k];
      sg += hv * wlds[2][jl][k];
      so += hv * wlds[3][jl][k];
    }
    // wave-level reduce over the 4 subs in this wave
    si += __shfl_down(si, 32); si += __shfl_down(si, 16);
    sf += __shfl_down(sf, 32); sf += __shfl_down(sf, 16);
    sg += __shfl_down(sg, 32); sg += __shfl_down(sg, 16);
    so += __shfl_down(so, 32); so += __shfl_down(so, 16);
    if ((tid & 63) < 16) {
      red[wv][0][b] = si; red[wv][1][b] = sf;
      red[wv][2][b] = sg; red[wv][3][b] = so;
    }
    __syncthreads();
    if (tid < 128) {
      int ajl = tid >> 6, ag = (tid >> 4) & 3, ab = tid & 15;
      gsum[ajl][ag][ab] = red[ajl * 4 + 0][ag][ab] + red[ajl * 4 + 1][ag][ab] +
                          red[ajl * 4 + 2][ag][ab] + red[ajl * 4 + 3][ag][ab];
    }
    __syncthreads();
    if (isPB) {
      float gi = xr0 + gsum[pjl][0][pb];
      float gf = xr1 + gsum[pjl][1][pb];
      float gg = xr2 + gsum[pjl][2][pb];
      float go_ = xr3 + gsum[pjl][3][pb];
      float iv = 1.f / (1.f + expf(-gi));
      float fv = 1.f / (1.f + expf(-gf));
      float gv = tanhf(gg);
      float ov = 1.f / (1.f + expf(-go_));
      float c = fv * creg + iv * gv;
      float h = ov * tanhf(c);
      creg = c;
      __hip_atomic_store(&hout[pj * 16 + pb], h,
                         __ATOMIC_RELAXED, __HIP_MEMORY_SCOPE_AGENT);
      xout[(size_t)(t * BATCH + pb) * H + pj] = h;
      if (t + 1 < T_STEPS) {  // prefetch next step's xih before barrier
        const float* xr = xih + (size_t)((t + 1) * BATCH + pb) * (4 * H);
        xr0 = xr[0 * H + pj]; xr1 = xr[1 * H + pj];
        xr2 = xr[2 * H + pj]; xr3 = xr[3 * H + pj];
      }
    }
    if (t < T_STEPS - 1) {
      __syncthreads();
      if (tid == 0) {
        __hip_atomic_fetch_add(arr, 1u, __ATOMIC_RELEASE, __HIP_MEMORY_SCOPE_AGENT);
        unsigned target = (unsigned)nblocks * (unsigned)(t + 2);
        unsigned gtarget = (unsigned)(t + 2);
        if (bid == 0) {
          for (;;) {
            unsigned s = 0;
            for (int i = 0; i < 8; ++i)
              s += __hip_atomic_load(sync + i * 32, __ATOMIC_ACQUIRE,
                                     __HIP_MEMORY_SCOPE_AGENT);
            if (s >= target) break;
            __builtin_amdgcn_s_sleep(8);
          }
          __hip_atomic_store(gop, gtarget, __ATOMIC_RELEASE,
                             __HIP_MEMORY_SCOPE_AGENT);
        } else {
          while (__hip_atomic_load(gop, __ATOMIC_ACQUIRE,
                                   __HIP_MEMORY_SCOPE_AGENT) < gtarget)
            __builtin_amdgcn_s_sleep(16);
        }
      }
      __syncthreads();
    }
  }
}

// a = softplus(out @ Wr^T + br) + 1e-8 ; d = max(|sum - cumsum|, 1e-6)
__global__ __launch_bounds__(256) void a_kernel(
    const float* __restrict__ xl2, const float* __restrict__ Wr,
    const float* __restrict__ br, float* __restrict__ a_buf,
    float* __restrict__ d_buf) {
#pragma clang fp contract(off)
  int n = blockIdx.x;
  int tid = threadIdx.x;
  int e = tid >> 4, lane = tid & 15;
  __shared__ float aa[NEXP];
  double partial = 0.;
  if (e < NEXP) {
    const float* row = xl2 + (size_t)n * D_LAST;
    const float* wr = Wr + (size_t)e * D_LAST;
    for (int k = lane; k < D_LAST; k += 16) partial += (double)row[k] * (double)wr[k];
  }
  for (int off = 8; off > 0; off >>= 1) partial += __shfl_down(partial, off, 16);
  if (e < NEXP && lane == 0) {
    float gf = (float)(partial + (double)br[e]);
    float t1 = exp_cr(-fabsf(gf));
    float t2 = log1p_cr(t1);
    float sp = fmaxf(gf, 0.0f) + t2;
    aa[e] = sp + 1e-8f;
  }
  __syncthreads();
  if (tid == 0) {
    double S = 0.;
    for (int j = 0; j < NEXP; ++j) S += (double)aa[j];
    double cum = 0.;
    for (int j = 0; j < NEXP; ++j) {
      cum += (double)aa[j];
      a_buf[(size_t)n * NEXP + j] = aa[j];
      d_buf[(size_t)n * NEXP + j] = (float)fmax(fabs(S - cum), 1e-6);
    }
  }
}

// E[Beta(a,d)] = a/(a+d)
__global__ void mean_kernel(const float* __restrict__ a_buf,
                            const float* __restrict__ d_buf,
                            float* __restrict__ s_buf) {
  int i = blockIdx.x * blockDim.x + threadIdx.x;
  if (i >= MROWS) return;
  double a = (double)a_buf[i], d = (double)d_buf[i];
  s_buf[i] = (float)(a / (a + d));
}

__global__ void pis_kernel(const float* __restrict__ s_buf, double* __restrict__ pis) {
  int n = blockIdx.x * blockDim.x + threadIdx.x;
  if (n >= NROWS) return;
  double cp = 1.0;
  for (int e = 0; e < NEXP; ++e) {
    if (e > 0) cp *= (1.0 - (double)s_buf[(size_t)n * NEXP + e - 1]);
    pis[(size_t)n * NEXP + e] = cp * (double)s_buf[(size_t)n * NEXP + e];
  }
}

// ---- bf16 conversions
__global__ void wdbf_kernel(const float* __restrict__ Wd, ushort* __restrict__ wdbf) {
  int i = blockIdx.x * blockDim.x + threadIdx.x;
  if (i >= NTOKPAD * KPAD) return;
  int r = i / KPAD, c = i % KPAD;
  wdbf[i] = (r < NTOKENS && c < D_INP) ? f2bf(Wd[(size_t)r * D_INP + c]) : 0;
}

__global__ void wlbf_kernel(const float* __restrict__ Wl, ushort* __restrict__ wlbf) {
  int i = blockIdx.x * blockDim.x + threadIdx.x;
  if (i >= NLATPAD * KLAT) return;
  int r = i / KLAT, c = i % KLAT;
  wlbf[i] = (r < NLAT && c < D_LAST) ? f2bf(Wl[(size_t)r * D_LAST + c]) : 0;
}

__global__ void xl2bf_kernel(const float* __restrict__ xl2, ushort* __restrict__ xbf) {
  int i = blockIdx.x * blockDim.x + threadIdx.x;
  if (i >= NROWS * KLAT) return;
  int r = i / KLAT, c = i % KLAT;
  xbf[i] = (c < D_LAST) ? f2bf(xl2[(size_t)r * D_LAST + c]) : 0;
}

__global__ void fill_tail(ushort* __restrict__ latbf) {
  int i = blockIdx.x * blockDim.x + threadIdx.x;
  if (i >= MROWS * 8) return;
  int r = i >> 3, c = i & 7;
  latbf[(size_t)r * KPAD + D_INP + c] = 0;
}

// latent = tanh(xl2 @ Wl^T + bl) via bf16 MFMA, scattered into latbf layout
__global__ __launch_bounds__(256) void lat_mfma(
    const ushort* __restrict__ xbf, const ushort* __restrict__ wlbf,
    const float* __restrict__ bl, ushort* __restrict__ latbf) {
  int bx = blockIdx.x, by = blockIdx.y;
  int tid = threadIdx.x;
  int wv = tid >> 6, lane = tid & 63;
  int l15 = lane & 15, lk = lane >> 4;
  int arow = by * 64 + wv * 16 + l15;
  const ushort* abase = xbf + (size_t)arow * KLAT + lk * 8;
  const ushort* bbase = wlbf + lk * 8;
  int col0 = bx * 64 + l15;
  f32x4 acc[4] = {{0,0,0,0},{0,0,0,0},{0,0,0,0},{0,0,0,0}};
  for (int kc = 0; kc < 20; ++kc) {
    bf16x8 a = *(const bf16x8*)(abase + kc * 32);
    bf16x8 b0 = *(const bf16x8*)(bbase + (size_t)(col0 +  0) * KLAT + kc * 32);
    bf16x8 b1 = *(const bf16x8*)(bbase + (size_t)(col0 + 16) * KLAT + kc * 32);
    bf16x8 b2 = *(const bf16x8*)(bbase + (size_t)(col0 + 32) * KLAT + kc * 32);
    bf16x8 b3 = *(const bf16x8*)(bbase + (size_t)(col0 + 48) * KLAT + kc * 32);
    acc[0] = __builtin_amdgcn_mfma_f32_16x16x32_bf16(a, b0, acc[0], 0, 0, 0);
    acc[1] = __builtin_amdgcn_mfma_f32_16x16x32_bf16(a, b1, acc[1], 0, 0, 0);
    acc[2] = __builtin_amdgcn_mfma_f32_16x16x32_bf16(a, b2, acc[2], 0, 0, 0);
    acc[3] = __builtin_amdgcn_mfma_f32_16x16x32_bf16(a, b3, acc[3], 0, 0, 0);
  }
#pragma unroll
  for (int j = 0; j < 4; ++j) {
    int m = by * 64 + wv * 16 + lk * 4 + j;
#pragma unroll
    for (int t = 0; t < 4; ++t) {
      int col = bx * 64 + t * 16 + l15;
      if (col < NLAT) {
        float v = tanhf(acc[t][j] + bl[col]);
        int e = col / D_INP, c = col % D_INP;
        latbf[(size_t)(m * NEXP + e) * KPAD + c] = f2bf(v);
      }
    }
  }
}

// ---- pass1: logits GEMM -> Z partials (XCD-swizzled)
__global__ __launch_bounds__(256) void pass1_mfma(
    const ushort* __restrict__ latbf, const ushort* __restrict__ wdbf,
    const float* __restrict__ bd, float* __restrict__ partials) {
  int bx, by;
  xcd_decode(blockIdx.x, &bx, &by);
  if (bx >= NBLK_N) return;
  int tid = threadIdx.x;
  int wv = tid >> 6, lane = tid & 63;
  int l15 = lane & 15, lk = lane >> 4;
  int arow = by * 64 + wv * 16 + l15;
  const ushort* abase = latbf + (size_t)arow * KPAD + lk * 8;
  const ushort* bbase = wdbf + lk * 8;
  int tok0 = bx * 64 + l15;
  f32x4 acc[4] = {{0,0,0,0},{0,0,0,0},{0,0,0,0},{0,0,0,0}};
  for (int kc = 0; kc < 9; ++kc) {
    bf16x8 a = *(const bf16x8*)(abase + kc * 32);
    bf16x8 b0 = *(const bf16x8*)(bbase + (size_t)(tok0 +  0) * KPAD + kc * 32);
    bf16x8 b1 = *(const bf16x8*)(bbase + (size_t)(tok0 + 16) * KPAD + kc * 32);
    bf16x8 b2 = *(const bf16x8*)(bbase + (size_t)(tok0 + 32) * KPAD + kc * 32);
    bf16x8 b3 = *(const bf16x8*)(bbase + (size_t)(tok0 + 48) * KPAD + kc * 32);
    acc[0] = __builtin_amdgcn_mfma_f32_16x16x32_bf16(a, b0, acc[0], 0, 0, 0);
    acc[1] = __builtin_amdgcn_mfma_f32_16x16x32_bf16(a, b1, acc[1], 0, 0, 0);
    acc[2] = __builtin_amdgcn_mfma_f32_16x16x32_bf16(a, b2, acc[2], 0, 0, 0);
    acc[3] = __builtin_amdgcn_mfma_f32_16x16x32_bf16(a, b3, acc[3], 0, 0, 0);
  }
  float bdv[4];
  bool tv[4];
#pragma unroll
  for (int t = 0; t < 4; ++t) {
    int tok = bx * 64 + t * 16 + l15;
    tv[t] = (tok < NTOKENS);
    bdv[t] = tv[t] ? bd[tok] : 0.f;
  }
#pragma unroll
  for (int j = 0; j < 4; ++j) {
    int crow = by * 64 + wv * 16 + lk * 4 + j;
    float v = 0.f;
#pragma unroll
    for (int t = 0; t < 4; ++t)
      if (tv[t]) v += expf(acc[t][j] + bdv[t]);
    v += __shfl_xor(v, 1);
    v += __shfl_xor(v, 2);
    v += __shfl_xor(v, 4);
    v += __shfl_xor(v, 8);
    if (l15 == 0) partials[(size_t)crow * NBLK_N + bx] = v;
  }
}

__global__ void zred_kernel(const float* __restrict__ partials, float* __restrict__ Zf) {
  int row = blockIdx.x * blockDim.x + threadIdx.x;
  if (row >= MROWS) return;
  float s = 0.f;
  const float* p = partials + (size_t)row * NBLK_N;
  for (int i = 0; i < NBLK_N; ++i) s += p[i];
  Zf[row] = s;
}

__global__ void c_kernel(const double* __restrict__ pis, const float* __restrict__ Zf,
                         float* __restrict__ cb) {
  int row = blockIdx.x * blockDim.x + threadIdx.x;
  if (row >= MROWS) return;
  cb[row] = (float)(log(pis[row]) - log((double)Zf[row]));
}

// ---- pass2: recompute logits, fold log-weights
__global__ __launch_bounds__(256) void pass2_mfma(
    const ushort* __restrict__ latbf, const ushort* __restrict__ wdbf,
    const float* __restrict__ bd, const float* __restrict__ cb,
    float* __restrict__ out) {
  __shared__ float Ct[64][65];
  int bx, by;
  xcd_decode(blockIdx.x, &bx, &by);
  if (bx >= NBLK_N) return;
  int tid = threadIdx.x;
  int wv = tid >> 6, lane = tid & 63;
  int l15 = lane & 15, lk = lane >> 4;
  int rl = wv * 16 + l15;
  bool areal = (rl < 60);
  const ushort* abase = latbf + (size_t)(by * 60 + (areal ? rl : 0)) * KPAD + lk * 8;
  const ushort* bbase = wdbf + lk * 8;
  int tok0 = bx * 64 + l15;
  f32x4 acc[4] = {{0,0,0,0},{0,0,0,0},{0,0,0,0},{0,0,0,0}};
  const bf16x8 zerov = {0,0,0,0,0,0,0,0};
  for (int kc = 0; kc < 9; ++kc) {
    bf16x8 a = areal ? *(const bf16x8*)(abase + kc * 32) : zerov;
    bf16x8 b0 = *(const bf16x8*)(bbase + (size_t)(tok0 +  0) * KPAD + kc * 32);
    bf16x8 b1 = *(const bf16x8*)(bbase + (size_t)(tok0 + 16) * KPAD + kc * 32);
    bf16x8 b2 = *(const bf16x8*)(bbase + (size_t)(tok0 + 32) * KPAD + kc * 32);
    bf16x8 b3 = *(const bf16x8*)(bbase + (size_t)(tok0 + 48) * KPAD + kc * 32);
    acc[0] = __builtin_amdgcn_mfma_f32_16x16x32_bf16(a, b0, acc[0], 0, 0, 0);
    acc[1] = __builtin_amdgcn_mfma_f32_16x16x32_bf16(a, b1, acc[1], 0, 0, 0);
    acc[2] = __builtin_amdgcn_mfma_f32_16x16x32_bf16(a, b2, acc[2], 0, 0, 0);
    acc[3] = __builtin_amdgcn_mfma_f32_16x16x32_bf16(a, b3, acc[3], 0, 0, 0);
  }
  float bdv[4];
  bool tv[4];
#pragma unroll
  for (int t = 0; t < 4; ++t) {
    int tok = bx * 64 + t * 16 + l15;
    tv[t] = (tok < NTOKENS);
    bdv[t] = tv[t] ? bd[tok] : 0.f;
  }
#pragma unroll
  for (int j = 0; j < 4; ++j) {
    int rowl = wv * 16 + lk * 4 + j;
    bool rreal = (rowl < 60);
    float cv = rreal ? cb[by * 60 + rowl] : 0.f;
#pragma unroll
    for (int t = 0; t < 4; ++t) {
      float term = (rreal && tv[t]) ? expf(acc[t][j] + bdv[t] + cv) : 0.f;
      Ct[rowl][t * 16 + l15] = term;
    }
  }
  __syncthreads();
  int g = tid >> 6, col = tid & 63;
  int tok = bx * 64 + col;
  if (tok < NTOKENS) {
    float s = 0.f;
#pragma unroll
    for (int e = 0; e < NEXP; ++e) s += Ct[g * 15 + e][col];
    out[(size_t)(by * 4 + g) * NTOKENS + tok] = logf(s + 1e-8f);
  }
}

// ---------------------------------------------------------------------------
extern "C" void kernel_launch(void* const* d_in, const int* in_sizes, int n_in,
                              void* d_out, int out_size, void* d_ws, size_t ws_size,
                              hipStream_t stream) {
  const int*   tokens = (const int*)d_in[0];
  const float* h0_0 = (const float*)d_in[1];
  const float* c0_0 = (const float*)d_in[2];
  const float* h0_1 = (const float*)d_in[3];
  const float* c0_1 = (const float*)d_in[4];
  const float* h0_2 = (const float*)d_in[5];
  const float* c0_2 = (const float*)d_in[6];
  const float* W_emb = (const float*)d_in[7];
  const float* Wih0 = (const float*)d_in[8];
  const float* Whh0 = (const float*)d_in[9];
  const float* bih0 = (const float*)d_in[10];
  const float* bhh0 = (const float*)d_in[11];
  const float* Wih1 = (const float*)d_in[12];
  const float* Whh1 = (const float*)d_in[13];
  const float* bih1 = (const float*)d_in[14];
  const float* bhh1 = (const float*)d_in[15];
  const float* Wih2 = (const float*)d_in[16];
  const float* Whh2 = (const float*)d_in[17];
  const float* bih2 = (const float*)d_in[18];
  const float* bhh2 = (const float*)d_in[19];
  const float* Wl = (const float*)d_in[20];
  const float* bl = (const float*)d_in[21];
  const float* Wr = (const float*)d_in[22];
  const float* br = (const float*)d_in[23];
  const float* Wd = (const float*)d_in[24];
  const float* bd = (const float*)d_in[25];
  float* out = (float*)d_out;

  char* base = (char*)d_ws;
  size_t off = 0;
  auto alloc = [&](size_t bytes) {
    off = (off + 255) & ~(size_t)255;
    void* r = base + off;
    off += bytes;
    return r;
  };
  double*   pid    = (double*)alloc(MROWS * sizeof(double));
  unsigned* ctr    = (unsigned*)alloc(3 * 2048);   // per-layer sync areas
  float*    emb    = (float*)alloc((size_t)NROWS * D_INP * 4);
  float*    xih    = (float*)alloc((size_t)NROWS * 4 * D_HID * 4);
  float*    xl0    = (float*)alloc((size_t)NROWS * D_HID * 4);
  float*    xl1    = (float*)alloc((size_t)NROWS * D_HID * 4);
  float*    xl2    = (float*)alloc((size_t)NROWS * D_LAST * 4);
  float*    hA     = (float*)alloc((size_t)D_HID * BATCH * 4);
  float*    hB     = (float*)alloc((size_t)D_HID * BATCH * 4);
  ushort*   xbf    = (ushort*)alloc((size_t)NROWS * KLAT * 2);
  ushort*   wlbf   = (ushort*)alloc((size_t)NLATPAD * KLAT * 2);
  ushort*   latbf  = (ushort*)alloc((size_t)MROWS * KPAD * 2);
  ushort*   wdbf   = (ushort*)alloc((size_t)NTOKPAD * KPAD * 2);
  float*    partials = (float*)alloc((size_t)MROWS * NBLK_N * 4);
  float*    Zf     = (float*)alloc(MROWS * 4);
  float*    cbuf   = (float*)alloc(MROWS * 4);
  float*    ab     = (float*)alloc(MROWS * 4);
  float*    db     = (float*)alloc(MROWS * 4);
  float*    sb     = (float*)alloc(MROWS * 4);
  if (ws_size < off) return;

  hipMemsetAsync((void*)ctr, 0, 3 * 2048, stream);
  wdbf_kernel<<<(NTOKPAD * KPAD + 255) / 256, 256, 0, stream>>>(Wd, wdbf);
  wlbf_kernel<<<(NLATPAD * KLAT + 255) / 256, 256, 0, stream>>>(Wl, wlbf);
  fill_tail<<<(MROWS * 8 + 255) / 256, 256, 0, stream>>>(latbf);
  embed_kernel<<<NROWS, 256, 0, stream>>>(tokens, W_emb, emb);

  auto launch_gemm = [&](const float* A, const float* B, const float* b0,
                         const float* b1, float* C, int M, int N, int K, int act) {
    dim3 grid((N + GBN - 1) / GBN, M / GBM);
    gemm_abt<<<grid, 256, 0, stream>>>(A, B, b0, b1, C, M, N, K, act);
  };

  unsigned* sy0 = ctr;
  unsigned* sy1 = ctr + 512;
  unsigned* sy2 = ctr + 1024;

  // ----- layer 0: 280 -> 960
  launch_gemm(emb, Wih0, bih0, bhh0, xih, NROWS, 4 * D_HID, D_INP, 0);
  lstm_persist<<<D_HID / 2, 512, 0, stream>>>(
      xih, Whh0, h0_0, c0_0, hA, hB, xl0, sy0, D_HID, D_HID / 2);
  // ----- layer 1: 960 -> 960
  launch_gemm(xl0, Wih1, bih1, bhh1, xih, NROWS, 4 * D_HID, D_HID, 0);
  lstm_persist<<<D_HID / 2, 512, 0, stream>>>(
      xih, Whh1, h0_1, c0_1, hA, hB, xl1, sy1, D_HID, D_HID / 2);
  // ----- layer 2: 960 -> 620
  launch_gemm(xl1, Wih2, bih2, bhh2, xih, NROWS, 4 * D_LAST, D_HID, 0);
  lstm_persist<<<D_LAST / 2, 512, 0, stream>>>(
      xih, Whh2, h0_2, c0_2, hA, hB, xl2, sy2, D_LAST, D_LAST / 2);

  // ----- latent = tanh(xl2 @ Wl^T + bl) via bf16 MFMA -> latbf
  xl2bf_kernel<<<(NROWS * KLAT + 255) / 256, 256, 0, stream>>>(xl2, xbf);
  {
    dim3 gl(NLATPAD / 64, NROWS / 64);
    lat_mfma<<<gl, 256, 0, stream>>>(xbf, wlbf, bl, latbf);
  }

  // ----- a, d -> E[Beta] -> pis
  a_kernel<<<NROWS, 256, 0, stream>>>(xl2, Wr, br, ab, db);
  mean_kernel<<<(MROWS + 255) / 256, 256, 0, stream>>>(ab, db, sb);
  pis_kernel<<<(NROWS + 255) / 256, 256, 0, stream>>>(sb, pid);

  // ----- pass1: Z partials (XCD-swizzled), reduce, fold weights
  pass1_mfma<<<BXPAD * (MROWS / 64), 256, 0, stream>>>(latbf, wdbf, bd, partials);
  zred_kernel<<<(MROWS + 255) / 256, 256, 0, stream>>>(partials, Zf);
  c_kernel<<<(MROWS + 255) / 256, 256, 0, stream>>>(pid, Zf, cbuf);

  // ----- pass2
  pass2_mfma<<<BXPAD * (NROWS / 4), 256, 0, stream>>>(latbf, wdbf, bd, cbuf, out);
}

// Round 10
// 13892.787 us; speedup vs baseline: 1.1222x; 1.1222x over previous
//
#include <hip/hip_runtime.h>
#include <hip/hip_bf16.h>
#include <stdint.h>

#define T_STEPS 64
#define BATCH   16
#define NROWS   1024          // T*B
#define NTOKENS 10000
#define NTOKPAD 10048         // 157*64
#define NBLK_N  157
#define BXPAD   160           // 8 XCDs * 20 bx-chunks
#define D_INP   280
#define D_HID   960
#define D_LAST  620
#define NEXP    15
#define KPAD    288           // 280 padded to 9*32
#define MROWS   (NROWS * NEXP)  // 15360
#define NLAT    4200          // NEXP*D_INP
#define NLATPAD 4224          // 66*64
#define KLAT    640           // 620 padded to 20*32
#define SYNCPAD 16            // 64B line per flag

typedef __attribute__((ext_vector_type(8))) short bf16x8;
typedef __attribute__((ext_vector_type(4))) float f32x4;

__device__ inline float log1p_cr(float x) { return (float)log1p((double)x); }
__device__ inline float exp_cr(float x)   { return (float)exp((double)x); }

__device__ inline ushort f2bf(float f) {
  uint32_t u = __float_as_uint(f);
  uint32_t r = (u + 0x7FFFu + ((u >> 16) & 1u)) >> 16;  // RNE
  return (ushort)r;
}

__device__ inline void xcd_decode(int bid, int* bx, int* by) {
  int x = bid & 7, k = bid >> 3;
  *bx = x * 20 + (k % 20);
  *by = k / 20;
}

// ---------------------------------------------------------------------------
__global__ void embed_kernel(const int* __restrict__ tokens,
                             const float* __restrict__ W_emb,
                             float* __restrict__ emb) {
  int n = blockIdx.x;
  int tok = tokens[n];
  for (int c = threadIdx.x; c < D_INP; c += blockDim.x)
    emb[(size_t)n * D_INP + c] = W_emb[(size_t)tok * D_INP + c];
}

// C[M][N] = A[M][K] @ B[N][K]^T + bias0 + bias1, f32 (feeds gates: precision)
#define GBM 128
#define GBN 128
#define GBK 16
__global__ __launch_bounds__(256) void gemm_abt(
    const float* __restrict__ A, const float* __restrict__ B,
    const float* __restrict__ bias0, const float* __restrict__ bias1,
    float* __restrict__ C, int M, int N, int K, int activation) {
  __shared__ float As[GBK][GBM + 4];
  __shared__ float Bs[GBK][GBN + 4];
  int bm = blockIdx.y * GBM, bn = blockIdx.x * GBN;
  int tx = threadIdx.x & 15, ty = threadIdx.x >> 4;
  int ml = threadIdx.x >> 2;
  int kc4 = (threadIdx.x & 3) * 4;
  float acc[8][8] = {};
  for (int k0 = 0; k0 < K; k0 += GBK) {
#pragma unroll
    for (int rep = 0; rep < 2; ++rep) {
      int m = ml + rep * 64;
      int gk = k0 + kc4;
      {
        int gm = bm + m;
        float4 v = {0.f, 0.f, 0.f, 0.f};
        if (gk + 3 < K) v = *(const float4*)&A[(size_t)gm * K + gk];
        else {
          float t0 = (gk + 0 < K) ? A[(size_t)gm * K + gk + 0] : 0.f;
          float t1 = (gk + 1 < K) ? A[(size_t)gm * K + gk + 1] : 0.f;
          float t2 = (gk + 2 < K) ? A[(size_t)gm * K + gk + 2] : 0.f;
          float t3 = (gk + 3 < K) ? A[(size_t)gm * K + gk + 3] : 0.f;
          v = {t0, t1, t2, t3};
        }
        As[kc4 + 0][m] = v.x; As[kc4 + 1][m] = v.y;
        As[kc4 + 2][m] = v.z; As[kc4 + 3][m] = v.w;
      }
      {
        int gn = bn + m;
        float4 v = {0.f, 0.f, 0.f, 0.f};
        if (gn < N) {
          if (gk + 3 < K) v = *(const float4*)&B[(size_t)gn * K + gk];
          else {
            float t0 = (gk + 0 < K) ? B[(size_t)gn * K + gk + 0] : 0.f;
            float t1 = (gk + 1 < K) ? B[(size_t)gn * K + gk + 1] : 0.f;
            float t2 = (gk + 2 < K) ? B[(size_t)gn * K + gk + 2] : 0.f;
            float t3 = (gk + 3 < K) ? B[(size_t)gn * K + gk + 3] : 0.f;
            v = {t0, t1, t2, t3};
          }
        }
        Bs[kc4 + 0][m] = v.x; Bs[kc4 + 1][m] = v.y;
        Bs[kc4 + 2][m] = v.z; Bs[kc4 + 3][m] = v.w;
      }
    }
    __syncthreads();
#pragma unroll
    for (int kk = 0; kk < GBK; ++kk) {
      float4 a0 = *(const float4*)&As[kk][ty * 8];
      float4 a1 = *(const float4*)&As[kk][ty * 8 + 4];
      float4 b0 = *(const float4*)&Bs[kk][tx * 8];
      float4 b1 = *(const float4*)&Bs[kk][tx * 8 + 4];
      float a[8] = {a0.x, a0.y, a0.z, a0.w, a1.x, a1.y, a1.z, a1.w};
      float b[8] = {b0.x, b0.y, b0.z, b0.w, b1.x, b1.y, b1.z, b1.w};
#pragma unroll
      for (int i = 0; i < 8; ++i)
#pragma unroll
        for (int j = 0; j < 8; ++j) acc[i][j] += a[i] * b[j];
    }
    __syncthreads();
  }
#pragma unroll
  for (int i = 0; i < 8; ++i) {
    int gm = bm + ty * 8 + i;
#pragma unroll
    for (int j = 0; j < 8; ++j) {
      int gn = bn + tx * 8 + j;
      if (gn < N) {
        float v = acc[i][j];
        if (bias0) v += bias0[gn];
        if (bias1) v += bias1[gn];
        if (activation == 1) v = tanhf(v);
        C[(size_t)gm * N + gn] = v;
      }
    }
  }
}

// ---------------------------------------------------------------------------
// Persistent LSTM v3: compute identical to v2 (j=2/block, 512 threads, LDS
// weights + h staging). Sync replaced by a parallel per-block-flag barrier:
// no shared hot lines -> no spin contention (v2's 78us/step killer).
__global__ __launch_bounds__(512) void lstm_persist(
    const float* __restrict__ xih,   // [T][B][4H]
    const float* __restrict__ Whh,   // [4H][H]
    const float* __restrict__ h0,    // [B][H]
    const float* __restrict__ c0,    // [B][H]
    float* __restrict__ hA,          // [H*16] ping
    float* __restrict__ hB,          // [H*16] pong
    float* __restrict__ xout,        // [T][B][H]
    unsigned* __restrict__ arrive,   // nblocks padded flags (64B apart)
    unsigned* __restrict__ go,       // nblocks padded flags
    int H, int nblocks) {
  __shared__ float wlds[4][2][D_HID];   // 30720 B
  __shared__ float hbuf[480 * 16];      // 30720 B
  __shared__ float red[8][4][16];
  __shared__ float gsum[2][4][16];
  const int tid = threadIdx.x;
  const int bid = blockIdx.x;
  const int jbase = bid * 2;
  const int jl = tid >> 8;            // 0..1
  const int sub = (tid >> 4) & 15;    // 0..15
  const int b = tid & 15;
  const int wv = tid >> 6;            // 0..7

  // stage weights: 8 rows (4 gates x 2 j) of H floats, coalesced
  for (int r = 0; r < 8; ++r) {
    int g = r >> 1, jj = r & 1;
    const float* src = Whh + (size_t)(g * H + jbase + jj) * H;
    for (int k = tid; k < H; k += 512) wlds[g][jj][k] = src[k];
  }

  const bool isPB = (tid < 32);
  const int pjl = tid >> 4;
  const int pb = tid & 15;
  const int pj = jbase + pjl;
  float creg = 0.f;
  float xr0 = 0.f, xr1 = 0.f, xr2 = 0.f, xr3 = 0.f;
  if (isPB) {
    creg = c0[(size_t)pb * H + pj];
    __hip_atomic_store(&hA[pj * 16 + pb], h0[(size_t)pb * H + pj],
                       __ATOMIC_RELAXED, __HIP_MEMORY_SCOPE_AGENT);
    const float* xr = xih + (size_t)(0 * BATCH + pb) * (4 * H);
    xr0 = xr[0 * H + pj]; xr1 = xr[1 * H + pj];
    xr2 = xr[2 * H + pj]; xr3 = xr[3 * H + pj];
  }

  // parallel-flag grid barrier: every spin target is a dedicated 64B line
  auto gbar = [&](unsigned epoch) {
    __syncthreads();
    if (bid == 0) {
      int i = 1 + tid;
      if (i < nblocks) {
        while (__hip_atomic_load(&arrive[i * SYNCPAD], __ATOMIC_ACQUIRE,
                                 __HIP_MEMORY_SCOPE_AGENT) < epoch)
          __builtin_amdgcn_s_sleep(2);
      }
      __syncthreads();
      if (i < nblocks)
        __hip_atomic_store(&go[i * SYNCPAD], epoch, __ATOMIC_RELEASE,
                           __HIP_MEMORY_SCOPE_AGENT);
    } else {
      if (tid == 0) {
        __hip_atomic_store(&arrive[bid * SYNCPAD], epoch, __ATOMIC_RELEASE,
                           __HIP_MEMORY_SCOPE_AGENT);
        while (__hip_atomic_load(&go[bid * SYNCPAD], __ATOMIC_ACQUIRE,
                                 __HIP_MEMORY_SCOPE_AGENT) < epoch)
          __builtin_amdgcn_s_sleep(2);
      }
    }
    __syncthreads();
  };

  gbar(1u);

  const int n1 = 480 * 16 / 4;
  const int n2 = (H - 480) * 16 / 4;
  for (int t = 0; t < T_STEPS; ++t) {
    const float* hin = (t & 1) ? hB : hA;
    float* hout = (t & 1) ? hA : hB;
    // ---- half 1: stage h[0:480) then dot
    for (int i = tid; i < n1; i += 512)
      ((float4*)hbuf)[i] = ((const float4*)hin)[i];
    __syncthreads();
    float si = 0.f, sf = 0.f, sg = 0.f, so = 0.f;
#pragma unroll 5
    for (int k = sub; k < 480; k += 16) {
      float hv = hbuf[k * 16 + b];
      si += hv * wlds[0][jl][k];
      sf += hv * wlds[1][jl][k];
      sg += hv * wlds[2][jl][k];
      so += hv * wlds[3][jl][k];
    }
    __syncthreads();
    // ---- half 2: stage h[480:H) then dot
    for (int i = tid; i < n2; i += 512)
      ((float4*)hbuf)[i] = ((const float4*)(hin + 480 * 16))[i];
    __syncthreads();
#pragma unroll 5
    for (int k = 480 + sub; k < H; k += 16) {
      float hv = hbuf[(k - 480) * 16 + b];
      si += hv * wlds[0][jl][k];
      sf += hv * wlds[1][jl][k];
      sg += hv * wlds[2][jl][k];
      so += hv * wlds[3][jl][k];
    }
    si += __shfl_down(si, 32); si += __shfl_down(si, 16);
    sf += __shfl_down(sf, 32); sf += __shfl_down(sf, 16);
    sg += __shfl_down(sg, 32); sg += __shfl_down(sg, 16);
    so += __shfl_down(so, 32); so += __shfl_down(so, 16);
    if ((tid & 63) < 16) {
      red[wv][0][b] = si; red[wv][1][b] = sf;
      red[wv][2][b] = sg; red[wv][3][b] = so;
    }
    __syncthreads();
    if (tid < 128) {
      int ajl = tid >> 6, ag = (tid >> 4) & 3, ab = tid & 15;
      gsum[ajl][ag][ab] = red[ajl * 4 + 0][ag][ab] + red[ajl * 4 + 1][ag][ab] +
                          red[ajl * 4 + 2][ag][ab] + red[ajl * 4 + 3][ag][ab];
    }
    __syncthreads();
    if (isPB) {
      float gi = xr0 + gsum[pjl][0][pb];
      float gf = xr1 + gsum[pjl][1][pb];
      float gg = xr2 + gsum[pjl][2][pb];
      float go_ = xr3 + gsum[pjl][3][pb];
      float iv = 1.f / (1.f + expf(-gi));
      float fv = 1.f / (1.f + expf(-gf));
      float gv = tanhf(gg);
      float ov = 1.f / (1.f + expf(-go_));
      float c = fv * creg + iv * gv;
      float h = ov * tanhf(c);
      creg = c;
      __hip_atomic_store(&hout[pj * 16 + pb], h,
                         __ATOMIC_RELAXED, __HIP_MEMORY_SCOPE_AGENT);
      xout[(size_t)(t * BATCH + pb) * H + pj] = h;
      if (t + 1 < T_STEPS) {
        const float* xr = xih + (size_t)((t + 1) * BATCH + pb) * (4 * H);
        xr0 = xr[0 * H + pj]; xr1 = xr[1 * H + pj];
        xr2 = xr[2 * H + pj]; xr3 = xr[3 * H + pj];
      }
    }
    if (t < T_STEPS - 1) gbar((unsigned)(t + 2));
  }
}

// a = softplus(out @ Wr^T + br) + 1e-8 ; d = max(|sum - cumsum|, 1e-6)
__global__ __launch_bounds__(256) void a_kernel(
    const float* __restrict__ xl2, const float* __restrict__ Wr,
    const float* __restrict__ br, float* __restrict__ a_buf,
    float* __restrict__ d_buf) {
#pragma clang fp contract(off)
  int n = blockIdx.x;
  int tid = threadIdx.x;
  int e = tid >> 4, lane = tid & 15;
  __shared__ float aa[NEXP];
  double partial = 0.;
  if (e < NEXP) {
    const float* row = xl2 + (size_t)n * D_LAST;
    const float* wr = Wr + (size_t)e * D_LAST;
    for (int k = lane; k < D_LAST; k += 16) partial += (double)row[k] * (double)wr[k];
  }
  for (int off = 8; off > 0; off >>= 1) partial += __shfl_down(partial, off, 16);
  if (e < NEXP && lane == 0) {
    float gf = (float)(partial + (double)br[e]);
    float t1 = exp_cr(-fabsf(gf));
    float t2 = log1p_cr(t1);
    float sp = fmaxf(gf, 0.0f) + t2;
    aa[e] = sp + 1e-8f;
  }
  __syncthreads();
  if (tid == 0) {
    double S = 0.;
    for (int j = 0; j < NEXP; ++j) S += (double)aa[j];
    double cum = 0.;
    for (int j = 0; j < NEXP; ++j) {
      cum += (double)aa[j];
      a_buf[(size_t)n * NEXP + j] = aa[j];
      d_buf[(size_t)n * NEXP + j] = (float)fmax(fabs(S - cum), 1e-6);
    }
  }
}

// E[Beta(a,d)] = a/(a+d)
__global__ void mean_kernel(const float* __restrict__ a_buf,
                            const float* __restrict__ d_buf,
                            float* __restrict__ s_buf) {
  int i = blockIdx.x * blockDim.x + threadIdx.x;
  if (i >= MROWS) return;
  double a = (double)a_buf[i], d = (double)d_buf[i];
  s_buf[i] = (float)(a / (a + d));
}

__global__ void pis_kernel(const float* __restrict__ s_buf, double* __restrict__ pis) {
  int n = blockIdx.x * blockDim.x + threadIdx.x;
  if (n >= NROWS) return;
  double cp = 1.0;
  for (int e = 0; e < NEXP; ++e) {
    if (e > 0) cp *= (1.0 - (double)s_buf[(size_t)n * NEXP + e - 1]);
    pis[(size_t)n * NEXP + e] = cp * (double)s_buf[(size_t)n * NEXP + e];
  }
}

// ---- bf16 conversions
__global__ void wdbf_kernel(const float* __restrict__ Wd, ushort* __restrict__ wdbf) {
  int i = blockIdx.x * blockDim.x + threadIdx.x;
  if (i >= NTOKPAD * KPAD) return;
  int r = i / KPAD, c = i % KPAD;
  wdbf[i] = (r < NTOKENS && c < D_INP) ? f2bf(Wd[(size_t)r * D_INP + c]) : 0;
}

__global__ void wlbf_kernel(const float* __restrict__ Wl, ushort* __restrict__ wlbf) {
  int i = blockIdx.x * blockDim.x + threadIdx.x;
  if (i >= NLATPAD * KLAT) return;
  int r = i / KLAT, c = i % KLAT;
  wlbf[i] = (r < NLAT && c < D_LAST) ? f2bf(Wl[(size_t)r * D_LAST + c]) : 0;
}

__global__ void xl2bf_kernel(const float* __restrict__ xl2, ushort* __restrict__ xbf) {
  int i = blockIdx.x * blockDim.x + threadIdx.x;
  if (i >= NROWS * KLAT) return;
  int r = i / KLAT, c = i % KLAT;
  xbf[i] = (c < D_LAST) ? f2bf(xl2[(size_t)r * D_LAST + c]) : 0;
}

__global__ void fill_tail(ushort* __restrict__ latbf) {
  int i = blockIdx.x * blockDim.x + threadIdx.x;
  if (i >= MROWS * 8) return;
  int r = i >> 3, c = i & 7;
  latbf[(size_t)r * KPAD + D_INP + c] = 0;
}

// latent = tanh(xl2 @ Wl^T + bl) via bf16 MFMA, scattered into latbf layout
__global__ __launch_bounds__(256) void lat_mfma(
    const ushort* __restrict__ xbf, const ushort* __restrict__ wlbf,
    const float* __restrict__ bl, ushort* __restrict__ latbf) {
  int bx = blockIdx.x, by = blockIdx.y;
  int tid = threadIdx.x;
  int wv = tid >> 6, lane = tid & 63;
  int l15 = lane & 15, lk = lane >> 4;
  int arow = by * 64 + wv * 16 + l15;
  const ushort* abase = xbf + (size_t)arow * KLAT + lk * 8;
  const ushort* bbase = wlbf + lk * 8;
  int col0 = bx * 64 + l15;
  f32x4 acc[4] = {{0,0,0,0},{0,0,0,0},{0,0,0,0},{0,0,0,0}};
  for (int kc = 0; kc < 20; ++kc) {
    bf16x8 a = *(const bf16x8*)(abase + kc * 32);
    bf16x8 b0 = *(const bf16x8*)(bbase + (size_t)(col0 +  0) * KLAT + kc * 32);
    bf16x8 b1 = *(const bf16x8*)(bbase + (size_t)(col0 + 16) * KLAT + kc * 32);
    bf16x8 b2 = *(const bf16x8*)(bbase + (size_t)(col0 + 32) * KLAT + kc * 32);
    bf16x8 b3 = *(const bf16x8*)(bbase + (size_t)(col0 + 48) * KLAT + kc * 32);
    acc[0] = __builtin_amdgcn_mfma_f32_16x16x32_bf16(a, b0, acc[0], 0, 0, 0);
    acc[1] = __builtin_amdgcn_mfma_f32_16x16x32_bf16(a, b1, acc[1], 0, 0, 0);
    acc[2] = __builtin_amdgcn_mfma_f32_16x16x32_bf16(a, b2, acc[2], 0, 0, 0);
    acc[3] = __builtin_amdgcn_mfma_f32_16x16x32_bf16(a, b3, acc[3], 0, 0, 0);
  }
#pragma unroll
  for (int j = 0; j < 4; ++j) {
    int m = by * 64 + wv * 16 + lk * 4 + j;
#pragma unroll
    for (int t = 0; t < 4; ++t) {
      int col = bx * 64 + t * 16 + l15;
      if (col < NLAT) {
        float v = tanhf(acc[t][j] + bl[col]);
        int e = col / D_INP, c = col % D_INP;
        latbf[(size_t)(m * NEXP + e) * KPAD + c] = f2bf(v);
      }
    }
  }
}

// ---- pass1: logits GEMM -> Z partials (XCD-swizzled)
__global__ __launch_bounds__(256) void pass1_mfma(
    const ushort* __restrict__ latbf, const ushort* __restrict__ wdbf,
    const float* __restrict__ bd, float* __restrict__ partials) {
  int bx, by;
  xcd_decode(blockIdx.x, &bx, &by);
  if (bx >= NBLK_N) return;
  int tid = threadIdx.x;
  int wv = tid >> 6, lane = tid & 63;
  int l15 = lane & 15, lk = lane >> 4;
  int arow = by * 64 + wv * 16 + l15;
  const ushort* abase = latbf + (size_t)arow * KPAD + lk * 8;
  const ushort* bbase = wdbf + lk * 8;
  int tok0 = bx * 64 + l15;
  f32x4 acc[4] = {{0,0,0,0},{0,0,0,0},{0,0,0,0},{0,0,0,0}};
  for (int kc = 0; kc < 9; ++kc) {
    bf16x8 a = *(const bf16x8*)(abase + kc * 32);
    bf16x8 b0 = *(const bf16x8*)(bbase + (size_t)(tok0 +  0) * KPAD + kc * 32);
    bf16x8 b1 = *(const bf16x8*)(bbase + (size_t)(tok0 + 16) * KPAD + kc * 32);
    bf16x8 b2 = *(const bf16x8*)(bbase + (size_t)(tok0 + 32) * KPAD + kc * 32);
    bf16x8 b3 = *(const bf16x8*)(bbase + (size_t)(tok0 + 48) * KPAD + kc * 32);
    acc[0] = __builtin_amdgcn_mfma_f32_16x16x32_bf16(a, b0, acc[0], 0, 0, 0);
    acc[1] = __builtin_amdgcn_mfma_f32_16x16x32_bf16(a, b1, acc[1], 0, 0, 0);
    acc[2] = __builtin_amdgcn_mfma_f32_16x16x32_bf16(a, b2, acc[2], 0, 0, 0);
    acc[3] = __builtin_amdgcn_mfma_f32_16x16x32_bf16(a, b3, acc[3], 0, 0, 0);
  }
  float bdv[4];
  bool tv[4];
#pragma unroll
  for (int t = 0; t < 4; ++t) {
    int tok = bx * 64 + t * 16 + l15;
    tv[t] = (tok < NTOKENS);
    bdv[t] = tv[t] ? bd[tok] : 0.f;
  }
#pragma unroll
  for (int j = 0; j < 4; ++j) {
    int crow = by * 64 + wv * 16 + lk * 4 + j;
    float v = 0.f;
#pragma unroll
    for (int t = 0; t < 4; ++t)
      if (tv[t]) v += expf(acc[t][j] + bdv[t]);
    v += __shfl_xor(v, 1);
    v += __shfl_xor(v, 2);
    v += __shfl_xor(v, 4);
    v += __shfl_xor(v, 8);
    if (l15 == 0) partials[(size_t)crow * NBLK_N + bx] = v;
  }
}

__global__ void zred_kernel(const float* __restrict__ partials, float* __restrict__ Zf) {
  int row = blockIdx.x * blockDim.x + threadIdx.x;
  if (row >= MROWS) return;
  float s = 0.f;
  const float* p = partials + (size_t)row * NBLK_N;
  for (int i = 0; i < NBLK_N; ++i) s += p[i];
  Zf[row] = s;
}

__global__ void c_kernel(const double* __restrict__ pis, const float* __restrict__ Zf,
                         float* __restrict__ cb) {
  int row = blockIdx.x * blockDim.x + threadIdx.x;
  if (row >= MROWS) return;
  cb[row] = (float)(log(pis[row]) - log((double)Zf[row]));
}

// ---- pass2: recompute logits, fold log-weights
__global__ __launch_bounds__(256) void pass2_mfma(
    const ushort* __restrict__ latbf, const ushort* __restrict__ wdbf,
    const float* __restrict__ bd, const float* __restrict__ cb,
    float* __restrict__ out) {
  __shared__ float Ct[64][65];
  int bx, by;
  xcd_decode(blockIdx.x, &bx, &by);
  if (bx >= NBLK_N) return;
  int tid = threadIdx.x;
  int wv = tid >> 6, lane = tid & 63;
  int l15 = lane & 15, lk = lane >> 4;
  int rl = wv * 16 + l15;
  bool areal = (rl < 60);
  const ushort* abase = latbf + (size_t)(by * 60 + (areal ? rl : 0)) * KPAD + lk * 8;
  const ushort* bbase = wdbf + lk * 8;
  int tok0 = bx * 64 + l15;
  f32x4 acc[4] = {{0,0,0,0},{0,0,0,0},{0,0,0,0},{0,0,0,0}};
  const bf16x8 zerov = {0,0,0,0,0,0,0,0};
  for (int kc = 0; kc < 9; ++kc) {
    bf16x8 a = areal ? *(const bf16x8*)(abase + kc * 32) : zerov;
    bf16x8 b0 = *(const bf16x8*)(bbase + (size_t)(tok0 +  0) * KPAD + kc * 32);
    bf16x8 b1 = *(const bf16x8*)(bbase + (size_t)(tok0 + 16) * KPAD + kc * 32);
    bf16x8 b2 = *(const bf16x8*)(bbase + (size_t)(tok0 + 32) * KPAD + kc * 32);
    bf16x8 b3 = *(const bf16x8*)(bbase + (size_t)(tok0 + 48) * KPAD + kc * 32);
    acc[0] = __builtin_amdgcn_mfma_f32_16x16x32_bf16(a, b0, acc[0], 0, 0, 0);
    acc[1] = __builtin_amdgcn_mfma_f32_16x16x32_bf16(a, b1, acc[1], 0, 0, 0);
    acc[2] = __builtin_amdgcn_mfma_f32_16x16x32_bf16(a, b2, acc[2], 0, 0, 0);
    acc[3] = __builtin_amdgcn_mfma_f32_16x16x32_bf16(a, b3, acc[3], 0, 0, 0);
  }
  float bdv[4];
  bool tv[4];
#pragma unroll
  for (int t = 0; t < 4; ++t) {
    int tok = bx * 64 + t * 16 + l15;
    tv[t] = (tok < NTOKENS);
    bdv[t] = tv[t] ? bd[tok] : 0.f;
  }
#pragma unroll
  for (int j = 0; j < 4; ++j) {
    int rowl = wv * 16 + lk * 4 + j;
    bool rreal = (rowl < 60);
    float cv = rreal ? cb[by * 60 + rowl] : 0.f;
#pragma unroll
    for (int t = 0; t < 4; ++t) {
      float term = (rreal && tv[t]) ? expf(acc[t][j] + bdv[t] + cv) : 0.f;
      Ct[rowl][t * 16 + l15] = term;
    }
  }
  __syncthreads();
  int g = tid >> 6, col = tid & 63;
  int tok = bx * 64 + col;
  if (tok < NTOKENS) {
    float s = 0.f;
#pragma unroll
    for (int e = 0; e < NEXP; ++e) s += Ct[g * 15 + e][col];
    out[(size_t)(by * 4 + g) * NTOKENS + tok] = logf(s + 1e-8f);
  }
}

// ---------------------------------------------------------------------------
extern "C" void kernel_launch(void* const* d_in, const int* in_sizes, int n_in,
                              void* d_out, int out_size, void* d_ws, size_t ws_size,
                              hipStream_t stream) {
  const int*   tokens = (const int*)d_in[0];
  const float* h0_0 = (const float*)d_in[1];
  const float* c0_0 = (const float*)d_in[2];
  const float* h0_1 = (const float*)d_in[3];
  const float* c0_1 = (const float*)d_in[4];
  const float* h0_2 = (const float*)d_in[5];
  const float* c0_2 = (const float*)d_in[6];
  const float* W_emb = (const float*)d_in[7];
  const float* Wih0 = (const float*)d_in[8];
  const float* Whh0 = (const float*)d_in[9];
  const float* bih0 = (const float*)d_in[10];
  const float* bhh0 = (const float*)d_in[11];
  const float* Wih1 = (const float*)d_in[12];
  const float* Whh1 = (const float*)d_in[13];
  const float* bih1 = (const float*)d_in[14];
  const float* bhh1 = (const float*)d_in[15];
  const float* Wih2 = (const float*)d_in[16];
  const float* Whh2 = (const float*)d_in[17];
  const float* bih2 = (const float*)d_in[18];
  const float* bhh2 = (const float*)d_in[19];
  const float* Wl = (const float*)d_in[20];
  const float* bl = (const float*)d_in[21];
  const float* Wr = (const float*)d_in[22];
  const float* br = (const float*)d_in[23];
  const float* Wd = (const float*)d_in[24];
  const float* bd = (const float*)d_in[25];
  float* out = (float*)d_out;

  char* base = (char*)d_ws;
  size_t off = 0;
  auto alloc = [&](size_t bytes) {
    off = (off + 255) & ~(size_t)255;
    void* r = base + off;
    off += bytes;
    return r;
  };
  double*   pid    = (double*)alloc(MROWS * sizeof(double));
  // 3 layers x {arrive, go} x 480 flags x 64B
  unsigned* syncb  = (unsigned*)alloc(3 * 2 * 480 * SYNCPAD * 4);
  float*    emb    = (float*)alloc((size_t)NROWS * D_INP * 4);
  float*    xih    = (float*)alloc((size_t)NROWS * 4 * D_HID * 4);
  float*    xl0    = (float*)alloc((size_t)NROWS * D_HID * 4);
  float*    xl1    = (float*)alloc((size_t)NROWS * D_HID * 4);
  float*    xl2    = (float*)alloc((size_t)NROWS * D_LAST * 4);
  float*    hA     = (float*)alloc((size_t)D_HID * BATCH * 4);
  float*    hB     = (float*)alloc((size_t)D_HID * BATCH * 4);
  ushort*   xbf    = (ushort*)alloc((size_t)NROWS * KLAT * 2);
  ushort*   wlbf   = (ushort*)alloc((size_t)NLATPAD * KLAT * 2);
  ushort*   latbf  = (ushort*)alloc((size_t)MROWS * KPAD * 2);
  ushort*   wdbf   = (ushort*)alloc((size_t)NTOKPAD * KPAD * 2);
  float*    partials = (float*)alloc((size_t)MROWS * NBLK_N * 4);
  float*    Zf     = (float*)alloc(MROWS * 4);
  float*    cbuf   = (float*)alloc(MROWS * 4);
  float*    ab     = (float*)alloc(MROWS * 4);
  float*    db     = (float*)alloc(MROWS * 4);
  float*    sb     = (float*)alloc(MROWS * 4);
  if (ws_size < off) return;

  hipMemsetAsync((void*)syncb, 0, 3 * 2 * 480 * SYNCPAD * 4, stream);
  wdbf_kernel<<<(NTOKPAD * KPAD + 255) / 256, 256, 0, stream>>>(Wd, wdbf);
  wlbf_kernel<<<(NLATPAD * KLAT + 255) / 256, 256, 0, stream>>>(Wl, wlbf);
  fill_tail<<<(MROWS * 8 + 255) / 256, 256, 0, stream>>>(latbf);
  embed_kernel<<<NROWS, 256, 0, stream>>>(tokens, W_emb, emb);

  auto launch_gemm = [&](const float* A, const float* B, const float* b0,
                         const float* b1, float* C, int M, int N, int K, int act) {
    dim3 grid((N + GBN - 1) / GBN, M / GBM);
    gemm_abt<<<grid, 256, 0, stream>>>(A, B, b0, b1, C, M, N, K, act);
  };

  const int FL = 480 * SYNCPAD;  // flags per array (uints)
  unsigned* ar0 = syncb + 0 * FL; unsigned* go0 = syncb + 1 * FL;
  unsigned* ar1 = syncb + 2 * FL; unsigned* go1 = syncb + 3 * FL;
  unsigned* ar2 = syncb + 4 * FL; unsigned* go2 = syncb + 5 * FL;

  // ----- layer 0: 280 -> 960
  launch_gemm(emb, Wih0, bih0, bhh0, xih, NROWS, 4 * D_HID, D_INP, 0);
  lstm_persist<<<D_HID / 2, 512, 0, stream>>>(
      xih, Whh0, h0_0, c0_0, hA, hB, xl0, ar0, go0, D_HID, D_HID / 2);
  // ----- layer 1: 960 -> 960
  launch_gemm(xl0, Wih1, bih1, bhh1, xih, NROWS, 4 * D_HID, D_HID, 0);
  lstm_persist<<<D_HID / 2, 512, 0, stream>>>(
      xih, Whh1, h0_1, c0_1, hA, hB, xl1, ar1, go1, D_HID, D_HID / 2);
  // ----- layer 2: 960 -> 620
  launch_gemm(xl1, Wih2, bih2, bhh2, xih, NROWS, 4 * D_LAST, D_HID, 0);
  lstm_persist<<<D_LAST / 2, 512, 0, stream>>>(
      xih, Whh2, h0_2, c0_2, hA, hB, xl2, ar2, go2, D_LAST, D_LAST / 2);

  // ----- latent = tanh(xl2 @ Wl^T + bl) via bf16 MFMA -> latbf
  xl2bf_kernel<<<(NROWS * KLAT + 255) / 256, 256, 0, stream>>>(xl2, xbf);
  {
    dim3 gl(NLATPAD / 64, NROWS / 64);
    lat_mfma<<<gl, 256, 0, stream>>>(xbf, wlbf, bl, latbf);
  }

  // ----- a, d -> E[Beta] -> pis
  a_kernel<<<NROWS, 256, 0, stream>>>(xl2, Wr, br, ab, db);
  mean_kernel<<<(MROWS + 255) / 256, 256, 0, stream>>>(ab, db, sb);
  pis_kernel<<<(NROWS + 255) / 256, 256, 0, stream>>>(sb, pid);

  // ----- pass1: Z partials (XCD-swizzled), reduce, fold weights
  pass1_mfma<<<BXPAD * (MROWS / 64), 256, 0, stream>>>(latbf, wdbf, bd, partials);
  zred_kernel<<<(MROWS + 255) / 256, 256, 0, stream>>>(partials, Zf);
  c_kernel<<<(MROWS + 255) / 256, 256, 0, stream>>>(pid, Zf, cbuf);

  // ----- pass2
  pass2_mfma<<<BXPAD * (NROWS / 4), 256, 0, stream>>>(latbf, wdbf, bd, cbuf, out);
}

// Round 11
// 6091.879 us; speedup vs baseline: 2.5592x; 2.2805x over previous
//
#include <hip/hip_runtime.h>
#include <hip/hip_bf16.h>
#include <stdint.h>

#define T_STEPS 64
#define BATCH   16
#define NROWS   1024          // T*B
#define NTOKENS 10000
#define NTOKPAD 10048         // 157*64
#define NBLK_N  157
#define BXPAD   160           // 8 XCDs * 20 bx-chunks
#define D_INP   280
#define D_HID   960
#define D_LAST  620
#define NEXP    15
#define KPAD    288           // 280 padded to 9*32
#define MROWS   (NROWS * NEXP)  // 15360
#define NLAT    4200          // NEXP*D_INP
#define NLATPAD 4224          // 66*64
#define KLAT    640           // 620 padded to 20*32
#define SYNCPAD 16            // 64B line per flag
#define MAXJ    16            // j outputs per block (one per wave)

typedef __attribute__((ext_vector_type(8))) short bf16x8;
typedef __attribute__((ext_vector_type(4))) float f32x4;

__device__ inline float log1p_cr(float x) { return (float)log1p((double)x); }
__device__ inline float exp_cr(float x)   { return (float)exp((double)x); }

__device__ inline ushort f2bf(float f) {
  uint32_t u = __float_as_uint(f);
  uint32_t r = (u + 0x7FFFu + ((u >> 16) & 1u)) >> 16;  // RNE
  return (ushort)r;
}
__device__ inline float bf2f(ushort v) {
  return __uint_as_float(((uint32_t)v) << 16);
}

__device__ inline void xcd_decode(int bid, int* bx, int* by) {
  int x = bid & 7, k = bid >> 3;
  *bx = x * 20 + (k % 20);
  *by = k / 20;
}

// ---------------------------------------------------------------------------
__global__ void embed_kernel(const int* __restrict__ tokens,
                             const float* __restrict__ W_emb,
                             float* __restrict__ emb) {
  int n = blockIdx.x;
  int tok = tokens[n];
  for (int c = threadIdx.x; c < D_INP; c += blockDim.x)
    emb[(size_t)n * D_INP + c] = W_emb[(size_t)tok * D_INP + c];
}

// C[M][N] = A[M][K] @ B[N][K]^T + bias0 + bias1, f32 (feeds gates: precision)
#define GBM 128
#define GBN 128
#define GBK 16
__global__ __launch_bounds__(256) void gemm_abt(
    const float* __restrict__ A, const float* __restrict__ B,
    const float* __restrict__ bias0, const float* __restrict__ bias1,
    float* __restrict__ C, int M, int N, int K, int activation) {
  __shared__ float As[GBK][GBM + 4];
  __shared__ float Bs[GBK][GBN + 4];
  int bm = blockIdx.y * GBM, bn = blockIdx.x * GBN;
  int tx = threadIdx.x & 15, ty = threadIdx.x >> 4;
  int ml = threadIdx.x >> 2;
  int kc4 = (threadIdx.x & 3) * 4;
  float acc[8][8] = {};
  for (int k0 = 0; k0 < K; k0 += GBK) {
#pragma unroll
    for (int rep = 0; rep < 2; ++rep) {
      int m = ml + rep * 64;
      int gk = k0 + kc4;
      {
        int gm = bm + m;
        float4 v = {0.f, 0.f, 0.f, 0.f};
        if (gk + 3 < K) v = *(const float4*)&A[(size_t)gm * K + gk];
        else {
          float t0 = (gk + 0 < K) ? A[(size_t)gm * K + gk + 0] : 0.f;
          float t1 = (gk + 1 < K) ? A[(size_t)gm * K + gk + 1] : 0.f;
          float t2 = (gk + 2 < K) ? A[(size_t)gm * K + gk + 2] : 0.f;
          float t3 = (gk + 3 < K) ? A[(size_t)gm * K + gk + 3] : 0.f;
          v = {t0, t1, t2, t3};
        }
        As[kc4 + 0][m] = v.x; As[kc4 + 1][m] = v.y;
        As[kc4 + 2][m] = v.z; As[kc4 + 3][m] = v.w;
      }
      {
        int gn = bn + m;
        float4 v = {0.f, 0.f, 0.f, 0.f};
        if (gn < N) {
          if (gk + 3 < K) v = *(const float4*)&B[(size_t)gn * K + gk];
          else {
            float t0 = (gk + 0 < K) ? B[(size_t)gn * K + gk + 0] : 0.f;
            float t1 = (gk + 1 < K) ? B[(size_t)gn * K + gk + 1] : 0.f;
            float t2 = (gk + 2 < K) ? B[(size_t)gn * K + gk + 2] : 0.f;
            float t3 = (gk + 3 < K) ? B[(size_t)gn * K + gk + 3] : 0.f;
            v = {t0, t1, t2, t3};
          }
        }
        Bs[kc4 + 0][m] = v.x; Bs[kc4 + 1][m] = v.y;
        Bs[kc4 + 2][m] = v.z; Bs[kc4 + 3][m] = v.w;
      }
    }
    __syncthreads();
#pragma unroll
    for (int kk = 0; kk < GBK; ++kk) {
      float4 a0 = *(const float4*)&As[kk][ty * 8];
      float4 a1 = *(const float4*)&As[kk][ty * 8 + 4];
      float4 b0 = *(const float4*)&Bs[kk][tx * 8];
      float4 b1 = *(const float4*)&Bs[kk][tx * 8 + 4];
      float a[8] = {a0.x, a0.y, a0.z, a0.w, a1.x, a1.y, a1.z, a1.w};
      float b[8] = {b0.x, b0.y, b0.z, b0.w, b1.x, b1.y, b1.z, b1.w};
#pragma unroll
      for (int i = 0; i < 8; ++i)
#pragma unroll
        for (int j = 0; j < 8; ++j) acc[i][j] += a[i] * b[j];
    }
    __syncthreads();
  }
#pragma unroll
  for (int i = 0; i < 8; ++i) {
    int gm = bm + ty * 8 + i;
#pragma unroll
    for (int j = 0; j < 8; ++j) {
      int gn = bn + tx * 8 + j;
      if (gn < N) {
        float v = acc[i][j];
        if (bias0) v += bias0[gn];
        if (bias1) v += bias1[gn];
        if (activation == 1) v = tanhf(v);
        C[(size_t)gm * N + gn] = v;
      }
    }
  }
}

// ---------------------------------------------------------------------------
// Persistent LSTM v4: 1024 threads/block, one j per wave (j=16/block) ->
// grid 60 (H=960) or 39 (H=620) blocks. Barrier participants 8x fewer than
// v3 (the measured cost law: ~0.15us per participant per step). Whh cached
// in LDS as bf16 (122.9KB) + f32 h staged in halves (30KB) = 150KB LDS.
__global__ __launch_bounds__(1024) void lstm_persist(
    const float* __restrict__ xih,   // [T][B][4H]
    const float* __restrict__ Whh,   // [4H][H]
    const float* __restrict__ h0,    // [B][H]
    const float* __restrict__ c0,    // [B][H]
    float* __restrict__ hA,          // [H*16] ping
    float* __restrict__ hB,          // [H*16] pong
    float* __restrict__ xout,        // [T][B][H]
    unsigned* __restrict__ arrive,   // padded flags (64B apart)
    unsigned* __restrict__ go,       // padded flags
    int H, int nblocks) {
  __shared__ ushort wlds[4][MAXJ][D_HID];  // bf16 weights, 122880 B
  __shared__ float hbuf[480 * 16];         // 30720 B (staged in halves)
  const int tid = threadIdx.x;
  const int bid = blockIdx.x;
  const int jbase = bid * MAXJ;
  const int wvj = tid >> 6;          // wave index == j-local 0..15
  const int lane = tid & 63;
  const int sub = lane >> 4;         // k-quarter 0..3
  const int b = lane & 15;
  const int j = jbase + wvj;
  const bool jok = (j < H);

  // stage weights (f32 -> bf16), coalesced: 64 rows (4 gates x 16 jl)
  for (int r = 0; r < 4 * MAXJ; ++r) {
    int g = r >> 4, jl = r & 15;
    int jj = jbase + jl;
    if (jj < H) {
      const float* src = Whh + (size_t)(g * H + jj) * H;
      for (int k = tid; k < H; k += 1024) wlds[g][jl][k] = f2bf(src[k]);
    }
  }

  const bool isPB = (sub == 0) && jok;
  float creg = 0.f;
  float xr0 = 0.f, xr1 = 0.f, xr2 = 0.f, xr3 = 0.f;
  if (isPB) {
    creg = c0[(size_t)b * H + j];
    __hip_atomic_store(&hA[j * 16 + b], h0[(size_t)b * H + j],
                       __ATOMIC_RELAXED, __HIP_MEMORY_SCOPE_AGENT);
    const float* xr = xih + (size_t)(0 * BATCH + b) * (4 * H);
    xr0 = xr[0 * H + j]; xr1 = xr[1 * H + j];
    xr2 = xr[2 * H + j]; xr3 = xr[3 * H + j];
  }

  // parallel-flag grid barrier (dedicated 64B line per block)
  auto gbar = [&](unsigned epoch) {
    __syncthreads();
    if (bid == 0) {
      if (tid == 0) __threadfence();
      __syncthreads();
      int i = 1 + tid;
      if (i < nblocks) {
        while (__hip_atomic_load(&arrive[i * SYNCPAD], __ATOMIC_ACQUIRE,
                                 __HIP_MEMORY_SCOPE_AGENT) < epoch)
          __builtin_amdgcn_s_sleep(8);
      }
      __syncthreads();
      if (i < nblocks)
        __hip_atomic_store(&go[i * SYNCPAD], epoch, __ATOMIC_RELEASE,
                           __HIP_MEMORY_SCOPE_AGENT);
    } else {
      if (tid == 0) {
        __threadfence();
        __hip_atomic_store(&arrive[bid * SYNCPAD], epoch, __ATOMIC_RELEASE,
                           __HIP_MEMORY_SCOPE_AGENT);
        while (__hip_atomic_load(&go[bid * SYNCPAD], __ATOMIC_ACQUIRE,
                                 __HIP_MEMORY_SCOPE_AGENT) < epoch)
          __builtin_amdgcn_s_sleep(8);
      }
    }
    __syncthreads();
  };

  gbar(1u);

  const int n1 = 480 * 16 / 4;                 // half-1 float4 count
  const int n2 = (H - 480) * 16 / 4;           // half-2 float4 count
  for (int t = 0; t < T_STEPS; ++t) {
    const float* hin = (t & 1) ? hB : hA;
    float* hout = (t & 1) ? hA : hB;
    // ---- half 1: stage h[0:480) then dot
    for (int i = tid; i < n1; i += 1024)
      ((float4*)hbuf)[i] = ((const float4*)hin)[i];
    __syncthreads();
    float si = 0.f, sf = 0.f, sg = 0.f, so = 0.f;
    if (jok) {
#pragma unroll 8
      for (int k = sub; k < 480; k += 4) {
        float hv = hbuf[k * 16 + b];
        si += hv * bf2f(wlds[0][wvj][k]);
        sf += hv * bf2f(wlds[1][wvj][k]);
        sg += hv * bf2f(wlds[2][wvj][k]);
        so += hv * bf2f(wlds[3][wvj][k]);
      }
    }
    __syncthreads();
    // ---- half 2: stage h[480:H) then dot
    for (int i = tid; i < n2; i += 1024)
      ((float4*)hbuf)[i] = ((const float4*)(hin + 480 * 16))[i];
    __syncthreads();
    if (jok) {
#pragma unroll 8
      for (int k = 480 + sub; k < H; k += 4) {
        float hv = hbuf[(k - 480) * 16 + b];
        si += hv * bf2f(wlds[0][wvj][k]);
        sf += hv * bf2f(wlds[1][wvj][k]);
        sg += hv * bf2f(wlds[2][wvj][k]);
        so += hv * bf2f(wlds[3][wvj][k]);
      }
    }
    // reduce over the 4 k-quarters (lanes stride 16 within wave64)
    si += __shfl_down(si, 32); si += __shfl_down(si, 16);
    sf += __shfl_down(sf, 32); sf += __shfl_down(sf, 16);
    sg += __shfl_down(sg, 32); sg += __shfl_down(sg, 16);
    so += __shfl_down(so, 32); so += __shfl_down(so, 16);
    if (isPB) {
      float gi = xr0 + si;
      float gf = xr1 + sf;
      float gg = xr2 + sg;
      float go_ = xr3 + so;
      float iv = 1.f / (1.f + expf(-gi));
      float fv = 1.f / (1.f + expf(-gf));
      float gv = tanhf(gg);
      float ov = 1.f / (1.f + expf(-go_));
      float c = fv * creg + iv * gv;
      float h = ov * tanhf(c);
      creg = c;
      __hip_atomic_store(&hout[j * 16 + b], h,
                         __ATOMIC_RELAXED, __HIP_MEMORY_SCOPE_AGENT);
      xout[(size_t)(t * BATCH + b) * H + j] = h;
      if (t + 1 < T_STEPS) {
        const float* xr = xih + (size_t)((t + 1) * BATCH + b) * (4 * H);
        xr0 = xr[0 * H + j]; xr1 = xr[1 * H + j];
        xr2 = xr[2 * H + j]; xr3 = xr[3 * H + j];
      }
    }
    if (t < T_STEPS - 1) gbar((unsigned)(t + 2));
  }
}

// a = softplus(out @ Wr^T + br) + 1e-8 ; d = max(|sum - cumsum|, 1e-6)
__global__ __launch_bounds__(256) void a_kernel(
    const float* __restrict__ xl2, const float* __restrict__ Wr,
    const float* __restrict__ br, float* __restrict__ a_buf,
    float* __restrict__ d_buf) {
#pragma clang fp contract(off)
  int n = blockIdx.x;
  int tid = threadIdx.x;
  int e = tid >> 4, lane = tid & 15;
  __shared__ float aa[NEXP];
  double partial = 0.;
  if (e < NEXP) {
    const float* row = xl2 + (size_t)n * D_LAST;
    const float* wr = Wr + (size_t)e * D_LAST;
    for (int k = lane; k < D_LAST; k += 16) partial += (double)row[k] * (double)wr[k];
  }
  for (int off = 8; off > 0; off >>= 1) partial += __shfl_down(partial, off, 16);
  if (e < NEXP && lane == 0) {
    float gf = (float)(partial + (double)br[e]);
    float t1 = exp_cr(-fabsf(gf));
    float t2 = log1p_cr(t1);
    float sp = fmaxf(gf, 0.0f) + t2;
    aa[e] = sp + 1e-8f;
  }
  __syncthreads();
  if (tid == 0) {
    double S = 0.;
    for (int j = 0; j < NEXP; ++j) S += (double)aa[j];
    double cum = 0.;
    for (int j = 0; j < NEXP; ++j) {
      cum += (double)aa[j];
      a_buf[(size_t)n * NEXP + j] = aa[j];
      d_buf[(size_t)n * NEXP + j] = (float)fmax(fabs(S - cum), 1e-6);
    }
  }
}

// E[Beta(a,d)] = a/(a+d)
__global__ void mean_kernel(const float* __restrict__ a_buf,
                            const float* __restrict__ d_buf,
                            float* __restrict__ s_buf) {
  int i = blockIdx.x * blockDim.x + threadIdx.x;
  if (i >= MROWS) return;
  double a = (double)a_buf[i], d = (double)d_buf[i];
  s_buf[i] = (float)(a / (a + d));
}

__global__ void pis_kernel(const float* __restrict__ s_buf, double* __restrict__ pis) {
  int n = blockIdx.x * blockDim.x + threadIdx.x;
  if (n >= NROWS) return;
  double cp = 1.0;
  for (int e = 0; e < NEXP; ++e) {
    if (e > 0) cp *= (1.0 - (double)s_buf[(size_t)n * NEXP + e - 1]);
    pis[(size_t)n * NEXP + e] = cp * (double)s_buf[(size_t)n * NEXP + e];
  }
}

// ---- bf16 conversions
__global__ void wdbf_kernel(const float* __restrict__ Wd, ushort* __restrict__ wdbf) {
  int i = blockIdx.x * blockDim.x + threadIdx.x;
  if (i >= NTOKPAD * KPAD) return;
  int r = i / KPAD, c = i % KPAD;
  wdbf[i] = (r < NTOKENS && c < D_INP) ? f2bf(Wd[(size_t)r * D_INP + c]) : 0;
}

__global__ void wlbf_kernel(const float* __restrict__ Wl, ushort* __restrict__ wlbf) {
  int i = blockIdx.x * blockDim.x + threadIdx.x;
  if (i >= NLATPAD * KLAT) return;
  int r = i / KLAT, c = i % KLAT;
  wlbf[i] = (r < NLAT && c < D_LAST) ? f2bf(Wl[(size_t)r * D_LAST + c]) : 0;
}

__global__ void xl2bf_kernel(const float* __restrict__ xl2, ushort* __restrict__ xbf) {
  int i = blockIdx.x * blockDim.x + threadIdx.x;
  if (i >= NROWS * KLAT) return;
  int r = i / KLAT, c = i % KLAT;
  xbf[i] = (c < D_LAST) ? f2bf(xl2[(size_t)r * D_LAST + c]) : 0;
}

__global__ void fill_tail(ushort* __restrict__ latbf) {
  int i = blockIdx.x * blockDim.x + threadIdx.x;
  if (i >= MROWS * 8) return;
  int r = i >> 3, c = i & 7;
  latbf[(size_t)r * KPAD + D_INP + c] = 0;
}

// latent = tanh(xl2 @ Wl^T + bl) via bf16 MFMA, scattered into latbf layout
__global__ __launch_bounds__(256) void lat_mfma(
    const ushort* __restrict__ xbf, const ushort* __restrict__ wlbf,
    const float* __restrict__ bl, ushort* __restrict__ latbf) {
  int bx = blockIdx.x, by = blockIdx.y;
  int tid = threadIdx.x;
  int wv = tid >> 6, lane = tid & 63;
  int l15 = lane & 15, lk = lane >> 4;
  int arow = by * 64 + wv * 16 + l15;
  const ushort* abase = xbf + (size_t)arow * KLAT + lk * 8;
  const ushort* bbase = wlbf + lk * 8;
  int col0 = bx * 64 + l15;
  f32x4 acc[4] = {{0,0,0,0},{0,0,0,0},{0,0,0,0},{0,0,0,0}};
  for (int kc = 0; kc < 20; ++kc) {
    bf16x8 a = *(const bf16x8*)(abase + kc * 32);
    bf16x8 b0 = *(const bf16x8*)(bbase + (size_t)(col0 +  0) * KLAT + kc * 32);
    bf16x8 b1 = *(const bf16x8*)(bbase + (size_t)(col0 + 16) * KLAT + kc * 32);
    bf16x8 b2 = *(const bf16x8*)(bbase + (size_t)(col0 + 32) * KLAT + kc * 32);
    bf16x8 b3 = *(const bf16x8*)(bbase + (size_t)(col0 + 48) * KLAT + kc * 32);
    acc[0] = __builtin_amdgcn_mfma_f32_16x16x32_bf16(a, b0, acc[0], 0, 0, 0);
    acc[1] = __builtin_amdgcn_mfma_f32_16x16x32_bf16(a, b1, acc[1], 0, 0, 0);
    acc[2] = __builtin_amdgcn_mfma_f32_16x16x32_bf16(a, b2, acc[2], 0, 0, 0);
    acc[3] = __builtin_amdgcn_mfma_f32_16x16x32_bf16(a, b3, acc[3], 0, 0, 0);
  }
#pragma unroll
  for (int j = 0; j < 4; ++j) {
    int m = by * 64 + wv * 16 + lk * 4 + j;
#pragma unroll
    for (int t = 0; t < 4; ++t) {
      int col = bx * 64 + t * 16 + l15;
      if (col < NLAT) {
        float v = tanhf(acc[t][j] + bl[col]);
        int e = col / D_INP, c = col % D_INP;
        latbf[(size_t)(m * NEXP + e) * KPAD + c] = f2bf(v);
      }
    }
  }
}

// ---- pass1: logits GEMM -> Z partials (XCD-swizzled)
__global__ __launch_bounds__(256) void pass1_mfma(
    const ushort* __restrict__ latbf, const ushort* __restrict__ wdbf,
    const float* __restrict__ bd, float* __restrict__ partials) {
  int bx, by;
  xcd_decode(blockIdx.x, &bx, &by);
  if (bx >= NBLK_N) return;
  int tid = threadIdx.x;
  int wv = tid >> 6, lane = tid & 63;
  int l15 = lane & 15, lk = lane >> 4;
  int arow = by * 64 + wv * 16 + l15;
  const ushort* abase = latbf + (size_t)arow * KPAD + lk * 8;
  const ushort* bbase = wdbf + lk * 8;
  int tok0 = bx * 64 + l15;
  f32x4 acc[4] = {{0,0,0,0},{0,0,0,0},{0,0,0,0},{0,0,0,0}};
  for (int kc = 0; kc < 9; ++kc) {
    bf16x8 a = *(const bf16x8*)(abase + kc * 32);
    bf16x8 b0 = *(const bf16x8*)(bbase + (size_t)(tok0 +  0) * KPAD + kc * 32);
    bf16x8 b1 = *(const bf16x8*)(bbase + (size_t)(tok0 + 16) * KPAD + kc * 32);
    bf16x8 b2 = *(const bf16x8*)(bbase + (size_t)(tok0 + 32) * KPAD + kc * 32);
    bf16x8 b3 = *(const bf16x8*)(bbase + (size_t)(tok0 + 48) * KPAD + kc * 32);
    acc[0] = __builtin_amdgcn_mfma_f32_16x16x32_bf16(a, b0, acc[0], 0, 0, 0);
    acc[1] = __builtin_amdgcn_mfma_f32_16x16x32_bf16(a, b1, acc[1], 0, 0, 0);
    acc[2] = __builtin_amdgcn_mfma_f32_16x16x32_bf16(a, b2, acc[2], 0, 0, 0);
    acc[3] = __builtin_amdgcn_mfma_f32_16x16x32_bf16(a, b3, acc[3], 0, 0, 0);
  }
  float bdv[4];
  bool tv[4];
#pragma unroll
  for (int t = 0; t < 4; ++t) {
    int tok = bx * 64 + t * 16 + l15;
    tv[t] = (tok < NTOKENS);
    bdv[t] = tv[t] ? bd[tok] : 0.f;
  }
#pragma unroll
  for (int j = 0; j < 4; ++j) {
    int crow = by * 64 + wv * 16 + lk * 4 + j;
    float v = 0.f;
#pragma unroll
    for (int t = 0; t < 4; ++t)
      if (tv[t]) v += expf(acc[t][j] + bdv[t]);
    v += __shfl_xor(v, 1);
    v += __shfl_xor(v, 2);
    v += __shfl_xor(v, 4);
    v += __shfl_xor(v, 8);
    if (l15 == 0) partials[(size_t)crow * NBLK_N + bx] = v;
  }
}

__global__ void zred_kernel(const float* __restrict__ partials, float* __restrict__ Zf) {
  int row = blockIdx.x * blockDim.x + threadIdx.x;
  if (row >= MROWS) return;
  float s = 0.f;
  const float* p = partials + (size_t)row * NBLK_N;
  for (int i = 0; i < NBLK_N; ++i) s += p[i];
  Zf[row] = s;
}

__global__ void c_kernel(const double* __restrict__ pis, const float* __restrict__ Zf,
                         float* __restrict__ cb) {
  int row = blockIdx.x * blockDim.x + threadIdx.x;
  if (row >= MROWS) return;
  cb[row] = (float)(log(pis[row]) - log((double)Zf[row]));
}

// ---- pass2: recompute logits, fold log-weights
__global__ __launch_bounds__(256) void pass2_mfma(
    const ushort* __restrict__ latbf, const ushort* __restrict__ wdbf,
    const float* __restrict__ bd, const float* __restrict__ cb,
    float* __restrict__ out) {
  __shared__ float Ct[64][65];
  int bx, by;
  xcd_decode(blockIdx.x, &bx, &by);
  if (bx >= NBLK_N) return;
  int tid = threadIdx.x;
  int wv = tid >> 6, lane = tid & 63;
  int l15 = lane & 15, lk = lane >> 4;
  int rl = wv * 16 + l15;
  bool areal = (rl < 60);
  const ushort* abase = latbf + (size_t)(by * 60 + (areal ? rl : 0)) * KPAD + lk * 8;
  const ushort* bbase = wdbf + lk * 8;
  int tok0 = bx * 64 + l15;
  f32x4 acc[4] = {{0,0,0,0},{0,0,0,0},{0,0,0,0},{0,0,0,0}};
  const bf16x8 zerov = {0,0,0,0,0,0,0,0};
  for (int kc = 0; kc < 9; ++kc) {
    bf16x8 a = areal ? *(const bf16x8*)(abase + kc * 32) : zerov;
    bf16x8 b0 = *(const bf16x8*)(bbase + (size_t)(tok0 +  0) * KPAD + kc * 32);
    bf16x8 b1 = *(const bf16x8*)(bbase + (size_t)(tok0 + 16) * KPAD + kc * 32);
    bf16x8 b2 = *(const bf16x8*)(bbase + (size_t)(tok0 + 32) * KPAD + kc * 32);
    bf16x8 b3 = *(const bf16x8*)(bbase + (size_t)(tok0 + 48) * KPAD + kc * 32);
    acc[0] = __builtin_amdgcn_mfma_f32_16x16x32_bf16(a, b0, acc[0], 0, 0, 0);
    acc[1] = __builtin_amdgcn_mfma_f32_16x16x32_bf16(a, b1, acc[1], 0, 0, 0);
    acc[2] = __builtin_amdgcn_mfma_f32_16x16x32_bf16(a, b2, acc[2], 0, 0, 0);
    acc[3] = __builtin_amdgcn_mfma_f32_16x16x32_bf16(a, b3, acc[3], 0, 0, 0);
  }
  float bdv[4];
  bool tv[4];
#pragma unroll
  for (int t = 0; t < 4; ++t) {
    int tok = bx * 64 + t * 16 + l15;
    tv[t] = (tok < NTOKENS);
    bdv[t] = tv[t] ? bd[tok] : 0.f;
  }
#pragma unroll
  for (int j = 0; j < 4; ++j) {
    int rowl = wv * 16 + lk * 4 + j;
    bool rreal = (rowl < 60);
    float cv = rreal ? cb[by * 60 + rowl] : 0.f;
#pragma unroll
    for (int t = 0; t < 4; ++t) {
      float term = (rreal && tv[t]) ? expf(acc[t][j] + bdv[t] + cv) : 0.f;
      Ct[rowl][t * 16 + l15] = term;
    }
  }
  __syncthreads();
  int g = tid >> 6, col = tid & 63;
  int tok = bx * 64 + col;
  if (tok < NTOKENS) {
    float s = 0.f;
#pragma unroll
    for (int e = 0; e < NEXP; ++e) s += Ct[g * 15 + e][col];
    out[(size_t)(by * 4 + g) * NTOKENS + tok] = logf(s + 1e-8f);
  }
}

// ---------------------------------------------------------------------------
extern "C" void kernel_launch(void* const* d_in, const int* in_sizes, int n_in,
                              void* d_out, int out_size, void* d_ws, size_t ws_size,
                              hipStream_t stream) {
  const int*   tokens = (const int*)d_in[0];
  const float* h0_0 = (const float*)d_in[1];
  const float* c0_0 = (const float*)d_in[2];
  const float* h0_1 = (const float*)d_in[3];
  const float* c0_1 = (const float*)d_in[4];
  const float* h0_2 = (const float*)d_in[5];
  const float* c0_2 = (const float*)d_in[6];
  const float* W_emb = (const float*)d_in[7];
  const float* Wih0 = (const float*)d_in[8];
  const float* Whh0 = (const float*)d_in[9];
  const float* bih0 = (const float*)d_in[10];
  const float* bhh0 = (const float*)d_in[11];
  const float* Wih1 = (const float*)d_in[12];
  const float* Whh1 = (const float*)d_in[13];
  const float* bih1 = (const float*)d_in[14];
  const float* bhh1 = (const float*)d_in[15];
  const float* Wih2 = (const float*)d_in[16];
  const float* Whh2 = (const float*)d_in[17];
  const float* bih2 = (const float*)d_in[18];
  const float* bhh2 = (const float*)d_in[19];
  const float* Wl = (const float*)d_in[20];
  const float* bl = (const float*)d_in[21];
  const float* Wr = (const float*)d_in[22];
  const float* br = (const float*)d_in[23];
  const float* Wd = (const float*)d_in[24];
  const float* bd = (const float*)d_in[25];
  float* out = (float*)d_out;

  char* base = (char*)d_ws;
  size_t off = 0;
  auto alloc = [&](size_t bytes) {
    off = (off + 255) & ~(size_t)255;
    void* r = base + off;
    off += bytes;
    return r;
  };
  double*   pid    = (double*)alloc(MROWS * sizeof(double));
  // 3 layers x {arrive, go} x 64 flags x 64B (grid <= 60)
  unsigned* syncb  = (unsigned*)alloc(3 * 2 * 64 * SYNCPAD * 4);
  float*    emb    = (float*)alloc((size_t)NROWS * D_INP * 4);
  float*    xih    = (float*)alloc((size_t)NROWS * 4 * D_HID * 4);
  float*    xl0    = (float*)alloc((size_t)NROWS * D_HID * 4);
  float*    xl1    = (float*)alloc((size_t)NROWS * D_HID * 4);
  float*    xl2    = (float*)alloc((size_t)NROWS * D_LAST * 4);
  float*    hA     = (float*)alloc((size_t)D_HID * BATCH * 4);
  float*    hB     = (float*)alloc((size_t)D_HID * BATCH * 4);
  ushort*   xbf    = (ushort*)alloc((size_t)NROWS * KLAT * 2);
  ushort*   wlbf   = (ushort*)alloc((size_t)NLATPAD * KLAT * 2);
  ushort*   latbf  = (ushort*)alloc((size_t)MROWS * KPAD * 2);
  ushort*   wdbf   = (ushort*)alloc((size_t)NTOKPAD * KPAD * 2);
  float*    partials = (float*)alloc((size_t)MROWS * NBLK_N * 4);
  float*    Zf     = (float*)alloc(MROWS * 4);
  float*    cbuf   = (float*)alloc(MROWS * 4);
  float*    ab     = (float*)alloc(MROWS * 4);
  float*    db     = (float*)alloc(MROWS * 4);
  float*    sb     = (float*)alloc(MROWS * 4);
  if (ws_size < off) return;

  hipMemsetAsync((void*)syncb, 0, 3 * 2 * 64 * SYNCPAD * 4, stream);
  wdbf_kernel<<<(NTOKPAD * KPAD + 255) / 256, 256, 0, stream>>>(Wd, wdbf);
  wlbf_kernel<<<(NLATPAD * KLAT + 255) / 256, 256, 0, stream>>>(Wl, wlbf);
  fill_tail<<<(MROWS * 8 + 255) / 256, 256, 0, stream>>>(latbf);
  embed_kernel<<<NROWS, 256, 0, stream>>>(tokens, W_emb, emb);

  auto launch_gemm = [&](const float* A, const float* B, const float* b0,
                         const float* b1, float* C, int M, int N, int K, int act) {
    dim3 grid((N + GBN - 1) / GBN, M / GBM);
    gemm_abt<<<grid, 256, 0, stream>>>(A, B, b0, b1, C, M, N, K, act);
  };

  const int FL = 64 * SYNCPAD;  // flags per array (uints)
  unsigned* ar0 = syncb + 0 * FL; unsigned* go0 = syncb + 1 * FL;
  unsigned* ar1 = syncb + 2 * FL; unsigned* go1 = syncb + 3 * FL;
  unsigned* ar2 = syncb + 4 * FL; unsigned* go2 = syncb + 5 * FL;

  const int NB0 = (D_HID + MAXJ - 1) / MAXJ;   // 60
  const int NB2 = (D_LAST + MAXJ - 1) / MAXJ;  // 39

  // ----- layer 0: 280 -> 960
  launch_gemm(emb, Wih0, bih0, bhh0, xih, NROWS, 4 * D_HID, D_INP, 0);
  lstm_persist<<<NB0, 1024, 0, stream>>>(
      xih, Whh0, h0_0, c0_0, hA, hB, xl0, ar0, go0, D_HID, NB0);
  // ----- layer 1: 960 -> 960
  launch_gemm(xl0, Wih1, bih1, bhh1, xih, NROWS, 4 * D_HID, D_HID, 0);
  lstm_persist<<<NB0, 1024, 0, stream>>>(
      xih, Whh1, h0_1, c0_1, hA, hB, xl1, ar1, go1, D_HID, NB0);
  // ----- layer 2: 960 -> 620
  launch_gemm(xl1, Wih2, bih2, bhh2, xih, NROWS, 4 * D_LAST, D_HID, 0);
  lstm_persist<<<NB2, 1024, 0, stream>>>(
      xih, Whh2, h0_2, c0_2, hA, hB, xl2, ar2, go2, D_LAST, NB2);

  // ----- latent = tanh(xl2 @ Wl^T + bl) via bf16 MFMA -> latbf
  xl2bf_kernel<<<(NROWS * KLAT + 255) / 256, 256, 0, stream>>>(xl2, xbf);
  {
    dim3 gl(NLATPAD / 64, NROWS / 64);
    lat_mfma<<<gl, 256, 0, stream>>>(xbf, wlbf, bl, latbf);
  }

  // ----- a, d -> E[Beta] -> pis
  a_kernel<<<NROWS, 256, 0, stream>>>(xl2, Wr, br, ab, db);
  mean_kernel<<<(MROWS + 255) / 256, 256, 0, stream>>>(ab, db, sb);
  pis_kernel<<<(NROWS + 255) / 256, 256, 0, stream>>>(sb, pid);

  // ----- pass1: Z partials (XCD-swizzled), reduce, fold weights
  pass1_mfma<<<BXPAD * (MROWS / 64), 256, 0, stream>>>(latbf, wdbf, bd, partials);
  zred_kernel<<<(MROWS + 255) / 256, 256, 0, stream>>>(partials, Zf);
  c_kernel<<<(MROWS + 255) / 256, 256, 0, stream>>>(pid, Zf, cbuf);

  // ----- pass2
  pass2_mfma<<<BXPAD * (NROWS / 4), 256, 0, stream>>>(latbf, wdbf, bd, cbuf, out);
}

// Round 12
// 3417.422 us; speedup vs baseline: 4.5620x; 1.7826x over previous
//
#include <hip/hip_runtime.h>
#include <hip/hip_bf16.h>
#include <stdint.h>

#define T_STEPS 64
#define BATCH   16
#define NROWS   1024          // T*B
#define NTOKENS 10000
#define NTOKPAD 10048         // 157*64
#define NBLK_N  157
#define BXPAD   160           // 8 XCDs * 20 bx-chunks
#define D_INP   280
#define D_HID   960
#define D_LAST  620
#define NEXP    15
#define KPAD    288           // 280 padded to 9*32
#define MROWS   (NROWS * NEXP)  // 15360
#define NLAT    4200          // NEXP*D_INP
#define NLATPAD 4224          // 66*64
#define KLAT    640           // 620 padded to 20*32
#define SYNCPAD 16            // 64B line per flag
#define HST     968           // LDS/global h stride (bf16) - 2-way-bank-free
#define GHSZ    (16 * HST)    // one h buffer (ushorts)
#define LWAVES  12            // waves per lstm block (768 threads)

typedef __attribute__((ext_vector_type(8))) short bf16x8;
typedef __attribute__((ext_vector_type(4))) float f32x4;

__device__ inline float log1p_cr(float x) { return (float)log1p((double)x); }
__device__ inline float exp_cr(float x)   { return (float)exp((double)x); }

__device__ inline ushort f2bf(float f) {
  uint32_t u = __float_as_uint(f);
  uint32_t r = (u + 0x7FFFu + ((u >> 16) & 1u)) >> 16;  // RNE
  return (ushort)r;
}
__device__ inline float bf2f(ushort v) {
  return __uint_as_float(((uint32_t)v) << 16);
}

__device__ inline void xcd_decode(int bid, int* bx, int* by) {
  int x = bid & 7, k = bid >> 3;
  *bx = x * 20 + (k % 20);
  *by = k / 20;
}

// ---------------------------------------------------------------------------
__global__ void embed_kernel(const int* __restrict__ tokens,
                             const float* __restrict__ W_emb,
                             float* __restrict__ emb) {
  int n = blockIdx.x;
  int tok = tokens[n];
  for (int c = threadIdx.x; c < D_INP; c += blockDim.x)
    emb[(size_t)n * D_INP + c] = W_emb[(size_t)tok * D_INP + c];
}

// C[M][N] = A[M][K] @ B[N][K]^T + bias0 + bias1, f32 (feeds gates: precision)
#define GBM 128
#define GBN 128
#define GBK 16
__global__ __launch_bounds__(256) void gemm_abt(
    const float* __restrict__ A, const float* __restrict__ B,
    const float* __restrict__ bias0, const float* __restrict__ bias1,
    float* __restrict__ C, int M, int N, int K, int activation) {
  __shared__ float As[GBK][GBM + 4];
  __shared__ float Bs[GBK][GBN + 4];
  int bm = blockIdx.y * GBM, bn = blockIdx.x * GBN;
  int tx = threadIdx.x & 15, ty = threadIdx.x >> 4;
  int ml = threadIdx.x >> 2;
  int kc4 = (threadIdx.x & 3) * 4;
  float acc[8][8] = {};
  for (int k0 = 0; k0 < K; k0 += GBK) {
#pragma unroll
    for (int rep = 0; rep < 2; ++rep) {
      int m = ml + rep * 64;
      int gk = k0 + kc4;
      {
        int gm = bm + m;
        float4 v = {0.f, 0.f, 0.f, 0.f};
        if (gk + 3 < K) v = *(const float4*)&A[(size_t)gm * K + gk];
        else {
          float t0 = (gk + 0 < K) ? A[(size_t)gm * K + gk + 0] : 0.f;
          float t1 = (gk + 1 < K) ? A[(size_t)gm * K + gk + 1] : 0.f;
          float t2 = (gk + 2 < K) ? A[(size_t)gm * K + gk + 2] : 0.f;
          float t3 = (gk + 3 < K) ? A[(size_t)gm * K + gk + 3] : 0.f;
          v = {t0, t1, t2, t3};
        }
        As[kc4 + 0][m] = v.x; As[kc4 + 1][m] = v.y;
        As[kc4 + 2][m] = v.z; As[kc4 + 3][m] = v.w;
      }
      {
        int gn = bn + m;
        float4 v = {0.f, 0.f, 0.f, 0.f};
        if (gn < N) {
          if (gk + 3 < K) v = *(const float4*)&B[(size_t)gn * K + gk];
          else {
            float t0 = (gk + 0 < K) ? B[(size_t)gn * K + gk + 0] : 0.f;
            float t1 = (gk + 1 < K) ? B[(size_t)gn * K + gk + 1] : 0.f;
            float t2 = (gk + 2 < K) ? B[(size_t)gn * K + gk + 2] : 0.f;
            float t3 = (gk + 3 < K) ? B[(size_t)gn * K + gk + 3] : 0.f;
            v = {t0, t1, t2, t3};
          }
        }
        Bs[kc4 + 0][m] = v.x; Bs[kc4 + 1][m] = v.y;
        Bs[kc4 + 2][m] = v.z; Bs[kc4 + 3][m] = v.w;
      }
    }
    __syncthreads();
#pragma unroll
    for (int kk = 0; kk < GBK; ++kk) {
      float4 a0 = *(const float4*)&As[kk][ty * 8];
      float4 a1 = *(const float4*)&As[kk][ty * 8 + 4];
      float4 b0 = *(const float4*)&Bs[kk][tx * 8];
      float4 b1 = *(const float4*)&Bs[kk][tx * 8 + 4];
      float a[8] = {a0.x, a0.y, a0.z, a0.w, a1.x, a1.y, a1.z, a1.w};
      float b[8] = {b0.x, b0.y, b0.z, b0.w, b1.x, b1.y, b1.z, b1.w};
#pragma unroll
      for (int i = 0; i < 8; ++i)
#pragma unroll
        for (int j = 0; j < 8; ++j) acc[i][j] += a[i] * b[j];
    }
    __syncthreads();
  }
#pragma unroll
  for (int i = 0; i < 8; ++i) {
    int gm = bm + ty * 8 + i;
#pragma unroll
    for (int j = 0; j < 8; ++j) {
      int gn = bn + tx * 8 + j;
      if (gn < N) {
        float v = acc[i][j];
        if (bias0) v += bias0[gn];
        if (bias1) v += bias1[gn];
        if (activation == 1) v = tanhf(v);
        C[(size_t)gm * N + gn] = v;
      }
    }
  }
}

// ---------------------------------------------------------------------------
// Persistent LSTM v5 (MFMA): 768 threads (12 waves), wave w owns tile
// T = bid*12+w covering all 4 gates of j in [4T,4T+4). Whh held in VGPRs as
// bf16 A-frags (KC*4 VGPR). h kept as bf16 hi+lo pair (2 MFMA/K-step => f32
// fidelity). Grid: 20 blocks (H=960), 13 (H=620) -> few barrier participants.
// C layout (m89): col=lane&15 (batch), row=(lane>>4)*4+reg; permuted rows
// put lane-group = gate, reg = j offset.
template<int KC>
__global__ __launch_bounds__(768) void lstm_mfma(
    const float* __restrict__ xih,   // [T][B][4H]
    const float* __restrict__ Whh,   // [4H][H]
    const float* __restrict__ h0,    // [B][H]
    const float* __restrict__ c0,    // [B][H]
    ushort* __restrict__ ghHi,       // [2][GHSZ] double-buffered h hi
    ushort* __restrict__ ghLo,       // [2][GHSZ]
    float* __restrict__ xout,        // [T][B][H]
    unsigned* __restrict__ arrive, unsigned* __restrict__ go_,
    int H, int NT, int nblocks) {
  __shared__ ushort hHi[GHSZ];
  __shared__ ushort hLo[GHSZ];
  const int tid = threadIdx.x;
  const int bid = blockIdx.x;
  const int w = tid >> 6;
  const int lane = tid & 63;
  const int lk = lane >> 4;       // lane group = gate (i,f,g,o)
  const int b15 = lane & 15;      // batch col / A row-local
  const int T = bid * LWAVES + w;
  const bool jok = (T < NT);

  // ---- A-frags: lane holds Whh[g][j][k0..k0+7] for its permuted row
  // A row-local r = b15 -> gate gr=(r>>2)&3, j = 4T + (r&3); k = kc*32+lk*8+e
  bf16x8 A[KC];
  {
    int gr = (b15 >> 2) & 3;
    int jr = jok ? (4 * T + (b15 & 3)) : 0;
    const float* arow = Whh + ((size_t)gr * H + jr) * H;
#pragma unroll
    for (int kc = 0; kc < KC; ++kc) {
      int k0 = kc * 32 + lk * 8;
      bf16x8 av;
      if (jok && k0 + 8 <= H) {
        float4 f0 = *(const float4*)&arow[k0];
        float4 f1 = *(const float4*)&arow[k0 + 4];
        av[0] = (short)f2bf(f0.x); av[1] = (short)f2bf(f0.y);
        av[2] = (short)f2bf(f0.z); av[3] = (short)f2bf(f0.w);
        av[4] = (short)f2bf(f1.x); av[5] = (short)f2bf(f1.y);
        av[6] = (short)f2bf(f1.z); av[7] = (short)f2bf(f1.w);
      } else {
#pragma unroll
        for (int e = 0; e < 8; ++e) {
          int k = k0 + e;
          float f = (jok && k < H) ? arow[k] : 0.f;
          av[e] = (short)f2bf(f);
        }
      }
      A[kc] = av;
    }
  }

  const bool isPB = (lk == 0) && jok;
  float creg[4] = {0.f, 0.f, 0.f, 0.f};
  if (isPB) {
#pragma unroll
    for (int jj = 0; jj < 4; ++jj)
      creg[jj] = c0[(size_t)b15 * H + 4 * T + jj];
  }

  // ---- init hfrag from h0 (hi+lo), zero pads
  for (int i = tid; i < 16 * KC * 32; i += 768) {
    int b = i / (KC * 32), j = i % (KC * 32);
    int idx = b * HST + j;
    if (j < H) {
      float f = h0[(size_t)b * H + j];
      ushort hi = f2bf(f);
      hHi[idx] = hi;
      hLo[idx] = f2bf(f - bf2f(hi));
    } else {
      hHi[idx] = 0; hLo[idx] = 0;
    }
  }
  __syncthreads();

  // parallel-flag grid barrier (dedicated 64B line per block)
  auto gbar = [&](unsigned epoch) {
    __syncthreads();
    if (bid == 0) {
      if (tid == 0) __threadfence();
      __syncthreads();
      int i = 1 + tid;
      if (i < nblocks) {
        while (__hip_atomic_load(&arrive[i * SYNCPAD], __ATOMIC_ACQUIRE,
                                 __HIP_MEMORY_SCOPE_AGENT) < epoch)
          __builtin_amdgcn_s_sleep(4);
      }
      __syncthreads();
      if (i < nblocks)
        __hip_atomic_store(&go_[i * SYNCPAD], epoch, __ATOMIC_RELEASE,
                           __HIP_MEMORY_SCOPE_AGENT);
    } else {
      if (tid == 0) {
        __threadfence();
        __hip_atomic_store(&arrive[bid * SYNCPAD], epoch, __ATOMIC_RELEASE,
                           __HIP_MEMORY_SCOPE_AGENT);
        while (__hip_atomic_load(&go_[bid * SYNCPAD], __ATOMIC_ACQUIRE,
                                 __HIP_MEMORY_SCOPE_AGENT) < epoch)
          __builtin_amdgcn_s_sleep(4);
      }
    }
    __syncthreads();
  };

  const ushort* bHi = hHi + b15 * HST + lk * 8;
  const ushort* bLo = hLo + b15 * HST + lk * 8;

  for (int t = 0; t < T_STEPS; ++t) {
    // ---- gate GEMM: acc = Whh_perm @ (h_hi + h_lo)
    f32x4 acc = {0.f, 0.f, 0.f, 0.f};
#pragma unroll
    for (int kc = 0; kc < KC; ++kc) {
      bf16x8 bh = *(const bf16x8*)(bHi + kc * 32);
      bf16x8 bl = *(const bf16x8*)(bLo + kc * 32);
      acc = __builtin_amdgcn_mfma_f32_16x16x32_bf16(A[kc], bh, acc, 0, 0, 0);
      acc = __builtin_amdgcn_mfma_f32_16x16x32_bf16(A[kc], bl, acc, 0, 0, 0);
    }
    // ---- add xih for this lane's gate; gather other gates via shfl
    float gv[4] = {0.f, 0.f, 0.f, 0.f};
    if (jok) {
      float4 xr = *(const float4*)&xih[(size_t)(t * BATCH + b15) * 4 * H +
                                       (size_t)lk * H + 4 * T];
      gv[0] = acc[0] + xr.x; gv[1] = acc[1] + xr.y;
      gv[2] = acc[2] + xr.z; gv[3] = acc[3] + xr.w;
    }
    float fF[4], fG[4], fO[4];
#pragma unroll
    for (int jj = 0; jj < 4; ++jj) {
      fF[jj] = __shfl(gv[jj], b15 + 16);
      fG[jj] = __shfl(gv[jj], b15 + 32);
      fO[jj] = __shfl(gv[jj], b15 + 48);
    }
    if (isPB) {
      float hv[4];
      ushort hhi[4], hlo[4];
#pragma unroll
      for (int jj = 0; jj < 4; ++jj) {
        float iv = 1.f / (1.f + expf(-gv[jj]));
        float fv = 1.f / (1.f + expf(-fF[jj]));
        float gg = tanhf(fG[jj]);
        float ov = 1.f / (1.f + expf(-fO[jj]));
        float c = fv * creg[jj] + iv * gg;
        float h = ov * tanhf(c);
        creg[jj] = c;
        hv[jj] = h;
        hhi[jj] = f2bf(h);
        hlo[jj] = f2bf(h - bf2f(hhi[jj]));
      }
      size_t gidx = (size_t)(t & 1) * GHSZ + b15 * HST + 4 * T;
      *(ushort4*)&ghHi[gidx] = ushort4{hhi[0], hhi[1], hhi[2], hhi[3]};
      *(ushort4*)&ghLo[gidx] = ushort4{hlo[0], hlo[1], hlo[2], hlo[3]};
      *(float4*)&xout[(size_t)(t * BATCH + b15) * H + 4 * T] =
          float4{hv[0], hv[1], hv[2], hv[3]};
    }
    if (t < T_STEPS - 1) {
      gbar((unsigned)(t + 1));
      // ---- restage h (hi+lo) from global into LDS
      const ushort* sH = ghHi + (size_t)(t & 1) * GHSZ;
      const ushort* sL = ghLo + (size_t)(t & 1) * GHSZ;
      const int UN = 16 * KC * 4;  // 16B units
      for (int u = tid; u < UN; u += 768) {
        int b = u / (KC * 4);
        int jc = (u % (KC * 4)) * 8;
        int idx = b * HST + jc;
        if (jc + 8 <= H) {
          *(uint4*)&hHi[idx] = *(const uint4*)&sH[idx];
          *(uint4*)&hLo[idx] = *(const uint4*)&sL[idx];
        } else {
#pragma unroll
          for (int e = 0; e < 8; ++e) {
            hHi[idx + e] = (jc + e < H) ? sH[idx + e] : (ushort)0;
            hLo[idx + e] = (jc + e < H) ? sL[idx + e] : (ushort)0;
          }
        }
      }
      __syncthreads();
    }
  }
}

// a = softplus(out @ Wr^T + br) + 1e-8 ; d = max(|sum - cumsum|, 1e-6)
__global__ __launch_bounds__(256) void a_kernel(
    const float* __restrict__ xl2, const float* __restrict__ Wr,
    const float* __restrict__ br, float* __restrict__ a_buf,
    float* __restrict__ d_buf) {
#pragma clang fp contract(off)
  int n = blockIdx.x;
  int tid = threadIdx.x;
  int e = tid >> 4, lane = tid & 15;
  __shared__ float aa[NEXP];
  double partial = 0.;
  if (e < NEXP) {
    const float* row = xl2 + (size_t)n * D_LAST;
    const float* wr = Wr + (size_t)e * D_LAST;
    for (int k = lane; k < D_LAST; k += 16) partial += (double)row[k] * (double)wr[k];
  }
  for (int off = 8; off > 0; off >>= 1) partial += __shfl_down(partial, off, 16);
  if (e < NEXP && lane == 0) {
    float gf = (float)(partial + (double)br[e]);
    float t1 = exp_cr(-fabsf(gf));
    float t2 = log1p_cr(t1);
    float sp = fmaxf(gf, 0.0f) + t2;
    aa[e] = sp + 1e-8f;
  }
  __syncthreads();
  if (tid == 0) {
    double S = 0.;
    for (int j = 0; j < NEXP; ++j) S += (double)aa[j];
    double cum = 0.;
    for (int j = 0; j < NEXP; ++j) {
      cum += (double)aa[j];
      a_buf[(size_t)n * NEXP + j] = aa[j];
      d_buf[(size_t)n * NEXP + j] = (float)fmax(fabs(S - cum), 1e-6);
    }
  }
}

// E[Beta(a,d)] = a/(a+d)
__global__ void mean_kernel(const float* __restrict__ a_buf,
                            const float* __restrict__ d_buf,
                            float* __restrict__ s_buf) {
  int i = blockIdx.x * blockDim.x + threadIdx.x;
  if (i >= MROWS) return;
  double a = (double)a_buf[i], d = (double)d_buf[i];
  s_buf[i] = (float)(a / (a + d));
}

__global__ void pis_kernel(const float* __restrict__ s_buf, double* __restrict__ pis) {
  int n = blockIdx.x * blockDim.x + threadIdx.x;
  if (n >= NROWS) return;
  double cp = 1.0;
  for (int e = 0; e < NEXP; ++e) {
    if (e > 0) cp *= (1.0 - (double)s_buf[(size_t)n * NEXP + e - 1]);
    pis[(size_t)n * NEXP + e] = cp * (double)s_buf[(size_t)n * NEXP + e];
  }
}

// ---- bf16 conversions
__global__ void wdbf_kernel(const float* __restrict__ Wd, ushort* __restrict__ wdbf) {
  int i = blockIdx.x * blockDim.x + threadIdx.x;
  if (i >= NTOKPAD * KPAD) return;
  int r = i / KPAD, c = i % KPAD;
  wdbf[i] = (r < NTOKENS && c < D_INP) ? f2bf(Wd[(size_t)r * D_INP + c]) : 0;
}

__global__ void wlbf_kernel(const float* __restrict__ Wl, ushort* __restrict__ wlbf) {
  int i = blockIdx.x * blockDim.x + threadIdx.x;
  if (i >= NLATPAD * KLAT) return;
  int r = i / KLAT, c = i % KLAT;
  wlbf[i] = (r < NLAT && c < D_LAST) ? f2bf(Wl[(size_t)r * D_LAST + c]) : 0;
}

__global__ void xl2bf_kernel(const float* __restrict__ xl2, ushort* __restrict__ xbf) {
  int i = blockIdx.x * blockDim.x + threadIdx.x;
  if (i >= NROWS * KLAT) return;
  int r = i / KLAT, c = i % KLAT;
  xbf[i] = (c < D_LAST) ? f2bf(xl2[(size_t)r * D_LAST + c]) : 0;
}

__global__ void fill_tail(ushort* __restrict__ latbf) {
  int i = blockIdx.x * blockDim.x + threadIdx.x;
  if (i >= MROWS * 8) return;
  int r = i >> 3, c = i & 7;
  latbf[(size_t)r * KPAD + D_INP + c] = 0;
}

// latent = tanh(xl2 @ Wl^T + bl) via bf16 MFMA, scattered into latbf layout
__global__ __launch_bounds__(256) void lat_mfma(
    const ushort* __restrict__ xbf, const ushort* __restrict__ wlbf,
    const float* __restrict__ bl, ushort* __restrict__ latbf) {
  int bx = blockIdx.x, by = blockIdx.y;
  int tid = threadIdx.x;
  int wv = tid >> 6, lane = tid & 63;
  int l15 = lane & 15, lk = lane >> 4;
  int arow = by * 64 + wv * 16 + l15;
  const ushort* abase = xbf + (size_t)arow * KLAT + lk * 8;
  const ushort* bbase = wlbf + lk * 8;
  int col0 = bx * 64 + l15;
  f32x4 acc[4] = {{0,0,0,0},{0,0,0,0},{0,0,0,0},{0,0,0,0}};
  for (int kc = 0; kc < 20; ++kc) {
    bf16x8 a = *(const bf16x8*)(abase + kc * 32);
    bf16x8 b0 = *(const bf16x8*)(bbase + (size_t)(col0 +  0) * KLAT + kc * 32);
    bf16x8 b1 = *(const bf16x8*)(bbase + (size_t)(col0 + 16) * KLAT + kc * 32);
    bf16x8 b2 = *(const bf16x8*)(bbase + (size_t)(col0 + 32) * KLAT + kc * 32);
    bf16x8 b3 = *(const bf16x8*)(bbase + (size_t)(col0 + 48) * KLAT + kc * 32);
    acc[0] = __builtin_amdgcn_mfma_f32_16x16x32_bf16(a, b0, acc[0], 0, 0, 0);
    acc[1] = __builtin_amdgcn_mfma_f32_16x16x32_bf16(a, b1, acc[1], 0, 0, 0);
    acc[2] = __builtin_amdgcn_mfma_f32_16x16x32_bf16(a, b2, acc[2], 0, 0, 0);
    acc[3] = __builtin_amdgcn_mfma_f32_16x16x32_bf16(a, b3, acc[3], 0, 0, 0);
  }
#pragma unroll
  for (int j = 0; j < 4; ++j) {
    int m = by * 64 + wv * 16 + lk * 4 + j;
#pragma unroll
    for (int t = 0; t < 4; ++t) {
      int col = bx * 64 + t * 16 + l15;
      if (col < NLAT) {
        float v = tanhf(acc[t][j] + bl[col]);
        int e = col / D_INP, c = col % D_INP;
        latbf[(size_t)(m * NEXP + e) * KPAD + c] = f2bf(v);
      }
    }
  }
}

// ---- pass1: logits GEMM -> Z partials (XCD-swizzled)
__global__ __launch_bounds__(256) void pass1_mfma(
    const ushort* __restrict__ latbf, const ushort* __restrict__ wdbf,
    const float* __restrict__ bd, float* __restrict__ partials) {
  int bx, by;
  xcd_decode(blockIdx.x, &bx, &by);
  if (bx >= NBLK_N) return;
  int tid = threadIdx.x;
  int wv = tid >> 6, lane = tid & 63;
  int l15 = lane & 15, lk = lane >> 4;
  int arow = by * 64 + wv * 16 + l15;
  const ushort* abase = latbf + (size_t)arow * KPAD + lk * 8;
  const ushort* bbase = wdbf + lk * 8;
  int tok0 = bx * 64 + l15;
  f32x4 acc[4] = {{0,0,0,0},{0,0,0,0},{0,0,0,0},{0,0,0,0}};
  for (int kc = 0; kc < 9; ++kc) {
    bf16x8 a = *(const bf16x8*)(abase + kc * 32);
    bf16x8 b0 = *(const bf16x8*)(bbase + (size_t)(tok0 +  0) * KPAD + kc * 32);
    bf16x8 b1 = *(const bf16x8*)(bbase + (size_t)(tok0 + 16) * KPAD + kc * 32);
    bf16x8 b2 = *(const bf16x8*)(bbase + (size_t)(tok0 + 32) * KPAD + kc * 32);
    bf16x8 b3 = *(const bf16x8*)(bbase + (size_t)(tok0 + 48) * KPAD + kc * 32);
    acc[0] = __builtin_amdgcn_mfma_f32_16x16x32_bf16(a, b0, acc[0], 0, 0, 0);
    acc[1] = __builtin_amdgcn_mfma_f32_16x16x32_bf16(a, b1, acc[1], 0, 0, 0);
    acc[2] = __builtin_amdgcn_mfma_f32_16x16x32_bf16(a, b2, acc[2], 0, 0, 0);
    acc[3] = __builtin_amdgcn_mfma_f32_16x16x32_bf16(a, b3, acc[3], 0, 0, 0);
  }
  float bdv[4];
  bool tv[4];
#pragma unroll
  for (int t = 0; t < 4; ++t) {
    int tok = bx * 64 + t * 16 + l15;
    tv[t] = (tok < NTOKENS);
    bdv[t] = tv[t] ? bd[tok] : 0.f;
  }
#pragma unroll
  for (int j = 0; j < 4; ++j) {
    int crow = by * 64 + wv * 16 + lk * 4 + j;
    float v = 0.f;
#pragma unroll
    for (int t = 0; t < 4; ++t)
      if (tv[t]) v += expf(acc[t][j] + bdv[t]);
    v += __shfl_xor(v, 1);
    v += __shfl_xor(v, 2);
    v += __shfl_xor(v, 4);
    v += __shfl_xor(v, 8);
    if (l15 == 0) partials[(size_t)crow * NBLK_N + bx] = v;
  }
}

__global__ void zred_kernel(const float* __restrict__ partials, float* __restrict__ Zf) {
  int row = blockIdx.x * blockDim.x + threadIdx.x;
  if (row >= MROWS) return;
  float s = 0.f;
  const float* p = partials + (size_t)row * NBLK_N;
  for (int i = 0; i < NBLK_N; ++i) s += p[i];
  Zf[row] = s;
}

__global__ void c_kernel(const double* __restrict__ pis, const float* __restrict__ Zf,
                         float* __restrict__ cb) {
  int row = blockIdx.x * blockDim.x + threadIdx.x;
  if (row >= MROWS) return;
  cb[row] = (float)(log(pis[row]) - log((double)Zf[row]));
}

// ---- pass2: recompute logits, fold log-weights
__global__ __launch_bounds__(256) void pass2_mfma(
    const ushort* __restrict__ latbf, const ushort* __restrict__ wdbf,
    const float* __restrict__ bd, const float* __restrict__ cb,
    float* __restrict__ out) {
  __shared__ float Ct[64][65];
  int bx, by;
  xcd_decode(blockIdx.x, &bx, &by);
  if (bx >= NBLK_N) return;
  int tid = threadIdx.x;
  int wv = tid >> 6, lane = tid & 63;
  int l15 = lane & 15, lk = lane >> 4;
  int rl = wv * 16 + l15;
  bool areal = (rl < 60);
  const ushort* abase = latbf + (size_t)(by * 60 + (areal ? rl : 0)) * KPAD + lk * 8;
  const ushort* bbase = wdbf + lk * 8;
  int tok0 = bx * 64 + l15;
  f32x4 acc[4] = {{0,0,0,0},{0,0,0,0},{0,0,0,0},{0,0,0,0}};
  const bf16x8 zerov = {0,0,0,0,0,0,0,0};
  for (int kc = 0; kc < 9; ++kc) {
    bf16x8 a = areal ? *(const bf16x8*)(abase + kc * 32) : zerov;
    bf16x8 b0 = *(const bf16x8*)(bbase + (size_t)(tok0 +  0) * KPAD + kc * 32);
    bf16x8 b1 = *(const bf16x8*)(bbase + (size_t)(tok0 + 16) * KPAD + kc * 32);
    bf16x8 b2 = *(const bf16x8*)(bbase + (size_t)(tok0 + 32) * KPAD + kc * 32);
    bf16x8 b3 = *(const bf16x8*)(bbase + (size_t)(tok0 + 48) * KPAD + kc * 32);
    acc[0] = __builtin_amdgcn_mfma_f32_16x16x32_bf16(a, b0, acc[0], 0, 0, 0);
    acc[1] = __builtin_amdgcn_mfma_f32_16x16x32_bf16(a, b1, acc[1], 0, 0, 0);
    acc[2] = __builtin_amdgcn_mfma_f32_16x16x32_bf16(a, b2, acc[2], 0, 0, 0);
    acc[3] = __builtin_amdgcn_mfma_f32_16x16x32_bf16(a, b3, acc[3], 0, 0, 0);
  }
  float bdv[4];
  bool tv[4];
#pragma unroll
  for (int t = 0; t < 4; ++t) {
    int tok = bx * 64 + t * 16 + l15;
    tv[t] = (tok < NTOKENS);
    bdv[t] = tv[t] ? bd[tok] : 0.f;
  }
#pragma unroll
  for (int j = 0; j < 4; ++j) {
    int rowl = wv * 16 + lk * 4 + j;
    bool rreal = (rowl < 60);
    float cv = rreal ? cb[by * 60 + rowl] : 0.f;
#pragma unroll
    for (int t = 0; t < 4; ++t) {
      float term = (rreal && tv[t]) ? expf(acc[t][j] + bdv[t] + cv) : 0.f;
      Ct[rowl][t * 16 + l15] = term;
    }
  }
  __syncthreads();
  int g = tid >> 6, col = tid & 63;
  int tok = bx * 64 + col;
  if (tok < NTOKENS) {
    float s = 0.f;
#pragma unroll
    for (int e = 0; e < NEXP; ++e) s += Ct[g * 15 + e][col];
    out[(size_t)(by * 4 + g) * NTOKENS + tok] = logf(s + 1e-8f);
  }
}

// ---------------------------------------------------------------------------
extern "C" void kernel_launch(void* const* d_in, const int* in_sizes, int n_in,
                              void* d_out, int out_size, void* d_ws, size_t ws_size,
                              hipStream_t stream) {
  const int*   tokens = (const int*)d_in[0];
  const float* h0_0 = (const float*)d_in[1];
  const float* c0_0 = (const float*)d_in[2];
  const float* h0_1 = (const float*)d_in[3];
  const float* c0_1 = (const float*)d_in[4];
  const float* h0_2 = (const float*)d_in[5];
  const float* c0_2 = (const float*)d_in[6];
  const float* W_emb = (const float*)d_in[7];
  const float* Wih0 = (const float*)d_in[8];
  const float* Whh0 = (const float*)d_in[9];
  const float* bih0 = (const float*)d_in[10];
  const float* bhh0 = (const float*)d_in[11];
  const float* Wih1 = (const float*)d_in[12];
  const float* Whh1 = (const float*)d_in[13];
  const float* bih1 = (const float*)d_in[14];
  const float* bhh1 = (const float*)d_in[15];
  const float* Wih2 = (const float*)d_in[16];
  const float* Whh2 = (const float*)d_in[17];
  const float* bih2 = (const float*)d_in[18];
  const float* bhh2 = (const float*)d_in[19];
  const float* Wl = (const float*)d_in[20];
  const float* bl = (const float*)d_in[21];
  const float* Wr = (const float*)d_in[22];
  const float* br = (const float*)d_in[23];
  const float* Wd = (const float*)d_in[24];
  const float* bd = (const float*)d_in[25];
  float* out = (float*)d_out;

  char* base = (char*)d_ws;
  size_t off = 0;
  auto alloc = [&](size_t bytes) {
    off = (off + 255) & ~(size_t)255;
    void* r = base + off;
    off += bytes;
    return r;
  };
  double*   pid    = (double*)alloc(MROWS * sizeof(double));
  unsigned* syncb  = (unsigned*)alloc(3 * 2 * 64 * SYNCPAD * 4);
  ushort*   ghHi   = (ushort*)alloc(2 * GHSZ * 2);
  ushort*   ghLo   = (ushort*)alloc(2 * GHSZ * 2);
  float*    emb    = (float*)alloc((size_t)NROWS * D_INP * 4);
  float*    xih    = (float*)alloc((size_t)NROWS * 4 * D_HID * 4);
  float*    xl0    = (float*)alloc((size_t)NROWS * D_HID * 4);
  float*    xl1    = (float*)alloc((size_t)NROWS * D_HID * 4);
  float*    xl2    = (float*)alloc((size_t)NROWS * D_LAST * 4);
  ushort*   xbf    = (ushort*)alloc((size_t)NROWS * KLAT * 2);
  ushort*   wlbf   = (ushort*)alloc((size_t)NLATPAD * KLAT * 2);
  ushort*   latbf  = (ushort*)alloc((size_t)MROWS * KPAD * 2);
  ushort*   wdbf   = (ushort*)alloc((size_t)NTOKPAD * KPAD * 2);
  float*    partials = (float*)alloc((size_t)MROWS * NBLK_N * 4);
  float*    Zf     = (float*)alloc(MROWS * 4);
  float*    cbuf   = (float*)alloc(MROWS * 4);
  float*    ab     = (float*)alloc(MROWS * 4);
  float*    db     = (float*)alloc(MROWS * 4);
  float*    sb     = (float*)alloc(MROWS * 4);
  if (ws_size < off) return;

  hipMemsetAsync((void*)syncb, 0, 3 * 2 * 64 * SYNCPAD * 4, stream);
  wdbf_kernel<<<(NTOKPAD * KPAD + 255) / 256, 256, 0, stream>>>(Wd, wdbf);
  wlbf_kernel<<<(NLATPAD * KLAT + 255) / 256, 256, 0, stream>>>(Wl, wlbf);
  fill_tail<<<(MROWS * 8 + 255) / 256, 256, 0, stream>>>(latbf);
  embed_kernel<<<NROWS, 256, 0, stream>>>(tokens, W_emb, emb);

  auto launch_gemm = [&](const float* A, const float* B, const float* b0,
                         const float* b1, float* C, int M, int N, int K, int act) {
    dim3 grid((N + GBN - 1) / GBN, M / GBM);
    gemm_abt<<<grid, 256, 0, stream>>>(A, B, b0, b1, C, M, N, K, act);
  };

  const int FL = 64 * SYNCPAD;
  unsigned* ar0 = syncb + 0 * FL; unsigned* go0 = syncb + 1 * FL;
  unsigned* ar1 = syncb + 2 * FL; unsigned* go1 = syncb + 3 * FL;
  unsigned* ar2 = syncb + 4 * FL; unsigned* go2 = syncb + 5 * FL;

  const int NT01 = D_HID / 4;    // 240 tiles
  const int NB01 = NT01 / LWAVES;          // 20 blocks
  const int NT2  = D_LAST / 4;   // 155 tiles
  const int NB2  = (NT2 + LWAVES - 1) / LWAVES;  // 13 blocks

  // ----- layer 0: 280 -> 960
  launch_gemm(emb, Wih0, bih0, bhh0, xih, NROWS, 4 * D_HID, D_INP, 0);
  lstm_mfma<30><<<NB01, 768, 0, stream>>>(
      xih, Whh0, h0_0, c0_0, ghHi, ghLo, xl0, ar0, go0, D_HID, NT01, NB01);
  // ----- layer 1: 960 -> 960
  launch_gemm(xl0, Wih1, bih1, bhh1, xih, NROWS, 4 * D_HID, D_HID, 0);
  lstm_mfma<30><<<NB01, 768, 0, stream>>>(
      xih, Whh1, h0_1, c0_1, ghHi, ghLo, xl1, ar1, go1, D_HID, NT01, NB01);
  // ----- layer 2: 960 -> 620
  launch_gemm(xl1, Wih2, bih2, bhh2, xih, NROWS, 4 * D_LAST, D_HID, 0);
  lstm_mfma<20><<<NB2, 768, 0, stream>>>(
      xih, Whh2, h0_2, c0_2, ghHi, ghLo, xl2, ar2, go2, D_LAST, NT2, NB2);

  // ----- latent = tanh(xl2 @ Wl^T + bl) via bf16 MFMA -> latbf
  xl2bf_kernel<<<(NROWS * KLAT + 255) / 256, 256, 0, stream>>>(xl2, xbf);
  {
    dim3 gl(NLATPAD / 64, NROWS / 64);
    lat_mfma<<<gl, 256, 0, stream>>>(xbf, wlbf, bl, latbf);
  }

  // ----- a, d -> E[Beta] -> pis
  a_kernel<<<NROWS, 256, 0, stream>>>(xl2, Wr, br, ab, db);
  mean_kernel<<<(MROWS + 255) / 256, 256, 0, stream>>>(ab, db, sb);
  pis_kernel<<<(NROWS + 255) / 256, 256, 0, stream>>>(sb, pid);

  // ----- pass1: Z partials (XCD-swizzled), reduce, fold weights
  pass1_mfma<<<BXPAD * (MROWS / 64), 256, 0, stream>>>(latbf, wdbf, bd, partials);
  zred_kernel<<<(MROWS + 255) / 256, 256, 0, stream>>>(partials, Zf);
  c_kernel<<<(MROWS + 255) / 256, 256, 0, stream>>>(pid, Zf, cbuf);

  // ----- pass2
  pass2_mfma<<<BXPAD * (NROWS / 4), 256, 0, stream>>>(latbf, wdbf, bd, cbuf, out);
}